// Round 11
// baseline (245.526 us; speedup 1.0000x reference)
//
#include <hip/hip_runtime.h>

typedef __attribute__((ext_vector_type(8))) short bfrag;   // 8 x bf16
typedef __attribute__((ext_vector_type(4))) float facc;    // mfma accumulator

__device__ __forceinline__ short f2bf(float f) {
    unsigned u = __float_as_uint(f);
    u += 0x7FFFu + ((u >> 16) & 1u);          // round-to-nearest-even
    return (short)(u >> 16);
}
__device__ __forceinline__ int refl12(int i) {
    int r = i % 24; if (r < 0) r += 24; return (r < 12) ? r : 23 - r;
}
__device__ __forceinline__ facc mfma16(bfrag a, bfrag b, facc c) {
    return __builtin_amdgcn_mfma_f32_16x16x32_bf16(a, b, c, 0, 0, 0);
}

// ws layout (element offsets in shorts)
#define WB1_E 0                         // [1152][160] bf16
#define WB2_E 184320                    // [576][288]  bf16
#define W1T_E 350208                    // [32][96]    bf16
#define W2T_E 353280                    // [16][32]    bf16
// theta (float, [B][6]) at byte offset 707584

#define XS1_STRIDE 296                  // shorts; 592B: 16B-aligned, bank-clean

// ---------------------------------------------------------------------------
// K0: expand conv/FC weights into GEMM-friendly bf16 matrices in ws
// ---------------------------------------------------------------------------
__global__ void k0_build(const float* __restrict__ k1w, const float* __restrict__ k2w,
                         const float* __restrict__ W1, const float* __restrict__ W2,
                         short* __restrict__ ws)
{
    const int NW1 = 1152 * 160, NW2 = 576 * 288, NT1 = 32 * 96, NT2 = 16 * 32;
    const int total = NW1 + NW2 + NT1 + NT2;
    for (int q = blockIdx.x * blockDim.x + threadIdx.x; q < total;
         q += gridDim.x * blockDim.x) {
        float val = 0.f;
        short* dst;
        if (q < NW1) {
            int n = q / 160, kk = q - n * 160;
            dst = ws + WB1_E + q;
            int p1 = n >> 5, r = n & 31;
            int hy = (r >> 4) & 1, hx = (r >> 3) & 1, c = r & 7;
            int yp = p1 / 6, xp = p1 - yp * 6;
            int y = 2 * yp + hy, xo = 2 * xp + hx;
            if (kk < 144) {
                int yi = kk / 12, xi = kk - yi * 12;
                int ky = yi - y + 3, kx = xi - xo + 3;
                if (ky >= 0 && ky < 7 && kx >= 0 && kx < 7)
                    val = k1w[(ky * 7 + kx) * 8 + c];
            }
        } else if (q < NW1 + NW2) {
            int qq = q - NW1;
            int n = qq / 288, k2 = qq - n * 288;
            dst = ws + WB2_E + qq;
            int q2 = n >> 6, r = n & 63, g = r >> 4, c2 = r & 15;
            int gy = g >> 1, gx = g & 1;
            int qy = q2 / 3, qx = q2 - qy * 3;
            int Y = 2 * qy + gy, X = 2 * qx + gx;
            int p1 = k2 >> 3, c1 = k2 & 7;
            int yp = p1 / 6, xp = p1 - yp * 6;
            int ky = yp - Y + 2, kx = xp - X + 2;
            if (c2 < 10 && ky >= 0 && ky < 5 && kx >= 0 && kx < 5)
                val = k2w[((ky * 5 + kx) * 8 + c1) * 10 + c2];
        } else if (q < NW1 + NW2 + NT1) {
            int qq = q - NW1 - NW2;
            int j = qq / 96, k = qq - j * 96;
            dst = ws + W1T_E + qq;
            if (k < 90) val = W1[k * 32 + j];
        } else {
            int qq = q - NW1 - NW2 - NT1;
            int t = qq / 32, k = qq - t * 32;
            dst = ws + W2T_E + qq;
            if (t < 6) val = W2[k * 6 + t];
        }
        *dst = f2bf(val);
    }
}

// ---------------------------------------------------------------------------
// K12: GEMM1 (x @ Wbig1, pool+relu -> xs1 in LDS) + GEMM2 (+pool+relu)
//      + FC1 + FC2 -> theta[B][6] in ws.  xs1 never touches HBM.
//      768 thr = 12 waves (3 waves/SIMD), 128 images/block.
//      GEMM1: 2 Mgrp x 6 Ngrp, 6 chunks/wave (balanced).
//      GEMM2: 36 jobs (9 q2 x 4 m-pairs), 3 jobs/wave (balanced).
// ---------------------------------------------------------------------------
__global__ __launch_bounds__(768) void k12_gemm(
    const float* __restrict__ x, const short* __restrict__ wb1,
    const short* __restrict__ wb2, const short* __restrict__ w1t,
    const short* __restrict__ w2t, const float* __restrict__ bc1,
    const float* __restrict__ bc2, const float* __restrict__ b1,
    const float* __restrict__ b2, float* __restrict__ theta, int B)
{
    __shared__ short xs1L[128 * XS1_STRIDE];  // 75.8 KB
    __shared__ short XS2[128 * 128];          // 32 KB, XOR-swizzled
    __shared__ short FC1[128 * 64];           // 16 KB, XOR-swizzled

    const int tid = threadIdx.x;
    const int l = tid & 63, w = tid >> 6;     // 12 waves
    const int lr = l & 15, lg = l >> 4;
    const long long blkbase = (long long)blockIdx.x * 128;

    // GEMM1 mapping: 2 Mgrp x 6 Ngrp
    const int mg = w / 6, ng = w - mg * 6;    // mg 0..1, ng 0..5
    const int mloc = mg * 64;

    // zero XS2 pad (cols 90..127 must be 0 for FC1)
    for (int q = tid; q < 2048; q += 768) {
        bfrag z = {0, 0, 0, 0, 0, 0, 0, 0};
        *(bfrag*)&XS2[q * 8] = z;
    }

    // ---- GEMM1: A fragments from global x (f32 -> bf16, registers) ----
    bfrag a[4][5];
    #pragma unroll
    for (int ms = 0; ms < 4; ++ms) {
        long long img = blkbase + mloc + ms * 16 + lr;
        if (img >= B) img = B - 1;
        const float* row = x + (size_t)img * 144;
        #pragma unroll
        for (int t = 0; t < 5; ++t) {
            const int k = t * 32 + lg * 8;
            bfrag f = {0, 0, 0, 0, 0, 0, 0, 0};
            if (k < 144) {
                float4 u0 = *(const float4*)(row + k);
                float4 u1 = *(const float4*)(row + k + 4);
                f[0] = f2bf(u0.x); f[1] = f2bf(u0.y);
                f[2] = f2bf(u0.z); f[3] = f2bf(u0.w);
                f[4] = f2bf(u1.x); f[5] = f2bf(u1.y);
                f[6] = f2bf(u1.z); f[7] = f2bf(u1.w);
            }
            a[ms][t] = f;
        }
    }
    const float bcv = bc1[l & 7];

    auto loadB1 = [&](bfrag (&bb)[2][5], int p1v) {
        const short* p = wb1 + (size_t)(p1v * 32 + lr) * 160 + lg * 8;
        #pragma unroll
        for (int nt = 0; nt < 2; ++nt)
            #pragma unroll
            for (int t = 0; t < 5; ++t)
                bb[nt][t] = *(const bfrag*)(p + (size_t)nt * 16 * 160 + t * 32);
    };
    auto compute1 = [&](bfrag (&bb)[2][5], int p1v) {
        facc acc[4][2];
        #pragma unroll
        for (int ms = 0; ms < 4; ++ms)
            #pragma unroll
            for (int nt = 0; nt < 2; ++nt)
                acc[ms][nt] = (facc){0.f, 0.f, 0.f, 0.f};
        #pragma unroll
        for (int t = 0; t < 5; ++t)
            #pragma unroll
            for (int nt = 0; nt < 2; ++nt)
                #pragma unroll
                for (int ms = 0; ms < 4; ++ms)
                    acc[ms][nt] = mfma16(a[ms][t], bb[nt][t], acc[ms][nt]);
        // pool (nt pools hy; shfl_xor(8) pools hx) + bias + relu + store
        #pragma unroll
        for (int ms = 0; ms < 4; ++ms)
            #pragma unroll
            for (int i = 0; i < 4; ++i) {
                float p = fmaxf(acc[ms][0][i], acc[ms][1][i]);
                p = fmaxf(p, __shfl_xor(p, 8));
                p = fmaxf(p + bcv, 0.f);
                if ((l & 15) < 8) {
                    int mi = mloc + ms * 16 + lg * 4 + i;
                    xs1L[mi * XS1_STRIDE + p1v * 8 + (l & 7)] = f2bf(p);
                }
            }
    };

    {   // 6 chunks/wave: p1 = ng + 6k, k = 0..5  (covers 0..35)
        bfrag c0[2][5], c1[2][5];
        loadB1(c0, ng);
        loadB1(c1, ng + 6);  compute1(c0, ng);
        loadB1(c0, ng + 12); compute1(c1, ng + 6);
        loadB1(c1, ng + 18); compute1(c0, ng + 12);
        loadB1(c0, ng + 24); compute1(c1, ng + 18);
        loadB1(c1, ng + 30); compute1(c0, ng + 24);
        compute1(c1, ng + 30);
    }
    __syncthreads();

    // ---- GEMM2: xs1L @ Wbig2, pool over g, bias+relu -> XS2 ----
    // 36 jobs = 9 q2 x 4 m-pairs; wave w does jobs 3w..3w+2 (balanced).
    const int c2 = lr;
    const float bcv2 = (c2 < 10) ? bc2[c2] : 0.f;

    auto loadB2 = [&](bfrag (&bb)[4], int q2v, int tv) {
        #pragma unroll
        for (int g = 0; g < 4; ++g)
            bb[g] = *(const bfrag*)(
                wb2 + (size_t)(q2v * 64 + g * 16 + lr) * 288 + tv * 32 + lg * 8);
    };

    #pragma unroll 1
    for (int J = 0; J < 3; ++J) {
        const int job = 3 * w + J;            // 0..35
        const int q2 = job >> 2;              // 0..8
        const int mBase = (job & 3) * 32;     // 0,32,64,96

        facc acc[2][4];
        #pragma unroll
        for (int ms = 0; ms < 2; ++ms)
            #pragma unroll
            for (int g = 0; g < 4; ++g)
                acc[ms][g] = (facc){0.f, 0.f, 0.f, 0.f};

        auto mstep2 = [&](bfrag (&bb)[4], int tv) {
            bfrag av[2];
            #pragma unroll
            for (int ms = 0; ms < 2; ++ms) {
                int m = mBase + ms * 16 + lr;
                av[ms] = *(const bfrag*)&xs1L[m * XS1_STRIDE + tv * 32 + lg * 8];
            }
            __builtin_amdgcn_s_setprio(1);
            #pragma unroll
            for (int g = 0; g < 4; ++g)
                #pragma unroll
                for (int ms = 0; ms < 2; ++ms)
                    acc[ms][g] = mfma16(av[ms], bb[g], acc[ms][g]);
            __builtin_amdgcn_s_setprio(0);
        };

        bfrag d0[4], d1[4];
        loadB2(d0, q2, 0);
        #pragma unroll 1
        for (int tp = 0; tp < 4; ++tp) {
            loadB2(d1, q2, 2 * tp + 1);
            mstep2(d0, 2 * tp);
            loadB2(d0, q2, 2 * tp + 2);
            mstep2(d1, 2 * tp + 1);
        }
        mstep2(d0, 8);

        #pragma unroll
        for (int ms = 0; ms < 2; ++ms)
            #pragma unroll
            for (int i = 0; i < 4; ++i) {
                float v = fmaxf(fmaxf(acc[ms][0][i], acc[ms][1][i]),
                                fmaxf(acc[ms][2][i], acc[ms][3][i]));
                v = fmaxf(v + bcv2, 0.f);
                if (c2 < 10) {
                    int mi = mBase + ms * 16 + lg * 4 + i;
                    int k = q2 * 10 + c2;
                    XS2[mi * 128 + (((k >> 3) ^ (mi & 7)) << 3) + (k & 7)] = f2bf(v);
                }
            }
    }
    __syncthreads();

    // ---- FC1: relu(xs2 @ W1 + b1) -> FC1 lds (waves 0-7: 4 mgrp x 2 ngrp) ----
    if (w < 8) {
        const int mg2 = w >> 1, nt = w & 1;
        facc acc[2];
        acc[0] = (facc){0.f, 0.f, 0.f, 0.f};
        acc[1] = (facc){0.f, 0.f, 0.f, 0.f};
        #pragma unroll
        for (int t = 0; t < 3; ++t) {
            const bfrag bv = *(const bfrag*)(w1t + (size_t)(nt * 16 + lr) * 96 + t * 32 + lg * 8);
            #pragma unroll
            for (int ms = 0; ms < 2; ++ms) {
                int m = mg2 * 32 + ms * 16 + lr;
                bfrag av = *(const bfrag*)&XS2[m * 128 + (((t * 4 + lg) ^ (m & 7)) << 3)];
                acc[ms] = mfma16(av, bv, acc[ms]);
            }
        }
        const int jcol = nt * 16 + lr;
        const float bj = b1[jcol];
        #pragma unroll
        for (int ms = 0; ms < 2; ++ms)
            #pragma unroll
            for (int i = 0; i < 4; ++i) {
                float v = fmaxf(acc[ms][i] + bj, 0.f);
                int mi = mg2 * 32 + ms * 16 + lg * 4 + i;
                FC1[mi * 64 + (((jcol >> 3) ^ (mi & 7)) << 3) + (jcol & 7)] = f2bf(v);
            }
    }
    __syncthreads();

    // ---- FC2: theta = (fc1 @ W2 + b2) / (1+1e-5) -> global ws ----
    if (w < 4) {
        facc acc[2];
        acc[0] = (facc){0.f, 0.f, 0.f, 0.f};
        acc[1] = (facc){0.f, 0.f, 0.f, 0.f};
        const bfrag bv = *(const bfrag*)(w2t + (size_t)lr * 32 + lg * 8);
        #pragma unroll
        for (int ms = 0; ms < 2; ++ms) {
            int m = w * 32 + ms * 16 + lr;
            bfrag av = *(const bfrag*)&FC1[m * 64 + ((lg ^ (m & 7)) << 3)];
            acc[ms] = mfma16(av, bv, acc[ms]);
        }
        if (lr < 6) {
            const float tb = b2[lr];
            const float inv = 1.0f / (1.0f + 1e-5f);
            #pragma unroll
            for (int ms = 0; ms < 2; ++ms)
                #pragma unroll
                for (int i = 0; i < 4; ++i) {
                    long long img = blkbase + w * 32 + ms * 16 + lg * 4 + i;
                    if (img < B) theta[img * 6 + lr] = (acc[ms][i] + tb) * inv;
                }
        }
    }
}

// ---------------------------------------------------------------------------
// K3: affine grid + bilinear sample; 64 images staged in LDS per block
// ---------------------------------------------------------------------------
__global__ __launch_bounds__(256) void k3_sample(
    const float* __restrict__ x, const float* __restrict__ theta,
    float* __restrict__ out, int B)
{
    __shared__ float xL[64 * 145];
    __shared__ float thL[64 * 6];
    const int tid = threadIdx.x;
    const long long blkbase = (long long)blockIdx.x * 64;

    const float4* xg4 = (const float4*)(x + blkbase * 144);
    for (int q = tid; q < 2304; q += 256) {
        int il = q / 36, c4 = q - il * 36;
        float4 v = make_float4(0.f, 0.f, 0.f, 0.f);
        if (blkbase + il < B) v = xg4[(size_t)il * 36 + c4];
        *(float4*)&xL[il * 145 + c4 * 4] = v;
    }
    for (int q = tid; q < 384; q += 256) {
        long long idx = blkbase * 6 + q;
        if (idx < (long long)B * 6) thL[q] = theta[idx];
    }
    __syncthreads();

    const int il = tid >> 2, quad = tid & 3;
    const long long img = blkbase + il;
    if (img >= B) return;

    const float t0 = thL[il * 6 + 0];
    const float t1 = thL[il * 6 + 1];
    const float t2 = thL[il * 6 + 2];
    const float t3 = thL[il * 6 + 3];
    const float t4 = thL[il * 6 + 4];
    const float t5 = thL[il * 6 + 5];
    const float* xr = &xL[il * 145];
    const float step = 2.0f / 11.0f;
    const float t0s = t0 * 5.5f, t3s = t3 * 5.5f;

    float o[36];
    #pragma unroll
    for (int rr = 0; rr < 3; ++rr) {
        const int iy = quad * 3 + rr;
        const float yn = -1.0f + iy * step;
        const float cx = (t1 * yn + t2 + 1.0f) * 5.5f;
        const float cy = (t4 * yn + t5 + 1.0f) * 5.5f;
        #pragma unroll
        for (int jx = 0; jx < 12; ++jx) {
            const float xn = -1.0f + jx * step;
            const float px = fmaf(t0s, xn, cx);
            const float py = fmaf(t3s, xn, cy);
            const float fy = floorf(py), fx = floorf(px);
            const float wy = py - fy,    wx = px - fx;
            const int ly = (int)fy, lx = (int)fx;
            const int y0 = refl12(ly), y1 = refl12(ly + 1);
            const int x0 = refl12(lx), x1 = refl12(lx + 1);
            const float v00 = xr[y0 * 12 + x0];
            const float v01 = xr[y0 * 12 + x1];
            const float v10 = xr[y1 * 12 + x0];
            const float v11 = xr[y1 * 12 + x1];
            const float r0 = v00 + wx * (v01 - v00);
            const float r1 = v10 + wx * (v11 - v10);
            o[rr * 12 + jx] = r0 + wy * (r1 - r0);
        }
    }
    float* op = out + (size_t)img * 144 + quad * 36;
    #pragma unroll
    for (int k = 0; k < 9; ++k)
        *(float4*)(op + 4 * k) = make_float4(o[4*k], o[4*k+1], o[4*k+2], o[4*k+3]);
}

extern "C" void kernel_launch(void* const* d_in, const int* in_sizes, int n_in,
                              void* d_out, int out_size, void* d_ws, size_t ws_size,
                              hipStream_t stream)
{
    const float* x   = (const float*)d_in[0];
    const float* k1w = (const float*)d_in[1];
    const float* bc1 = (const float*)d_in[2];
    const float* k2w = (const float*)d_in[3];
    const float* bc2 = (const float*)d_in[4];
    const float* W1  = (const float*)d_in[5];
    const float* b1  = (const float*)d_in[6];
    const float* W2  = (const float*)d_in[7];
    const float* b2  = (const float*)d_in[8];
    float* out = (float*)d_out;
    const int B = in_sizes[0] / 144;

    short* ws = (short*)d_ws;
    short* wb1 = ws + WB1_E;
    short* wb2 = ws + WB2_E;
    short* w1t = ws + W1T_E;
    short* w2t = ws + W2T_E;
    float* theta = (float*)((char*)d_ws + 707584);

    hipLaunchKernelGGL(k0_build, dim3(512), dim3(256), 0, stream,
                       k1w, k2w, W1, W2, ws);

    const int nb = (B + 127) / 128;
    hipLaunchKernelGGL(k12_gemm, dim3(nb), dim3(768), 0, stream,
                       x, wb1, wb2, w1t, w2t, bc1, bc2, b1, b2, theta, B);

    const int nb3 = (int)((B + 63) / 64);
    hipLaunchKernelGGL(k3_sample, dim3(nb3), dim3(256), 0, stream,
                       x, theta, out, B);
}

// Round 12
// 211.754 us; speedup vs baseline: 1.1595x; 1.1595x over previous
//
#include <hip/hip_runtime.h>

typedef __attribute__((ext_vector_type(8))) short bfrag;   // 8 x bf16
typedef __attribute__((ext_vector_type(4))) float facc;    // mfma accumulator

__device__ __forceinline__ short f2bf(float f) {
    unsigned u = __float_as_uint(f);
    u += 0x7FFFu + ((u >> 16) & 1u);          // round-to-nearest-even
    return (short)(u >> 16);
}
__device__ __forceinline__ float maxpair8(float p) {
    // max(p[lane], p[lane^8]) within 16-lane rows; row_ror:8 == xor 8 (mod 16).
    // Intrinsic DPP (not raw asm) -> compiler inserts required hazard nops.
    int r = __builtin_amdgcn_update_dpp(0, __float_as_int(p),
                                        0x128 /*row_ror:8*/, 0xf, 0xf, true);
    return fmaxf(p, __int_as_float(r));
}
__device__ __forceinline__ int refl12(int i) {
    int r = i % 24; if (r < 0) r += 24; return (r < 12) ? r : 23 - r;
}
__device__ __forceinline__ facc mfma16(bfrag a, bfrag b, facc c) {
    return __builtin_amdgcn_mfma_f32_16x16x32_bf16(a, b, c, 0, 0, 0);
}

// ws layout (element offsets in shorts)
#define WB1_E 0                         // [1152][160] bf16
#define WB2_E 184320                    // [576][288]  bf16
#define W1T_E 350208                    // [32][96]    bf16
#define W2T_E 353280                    // [16][32]    bf16
// theta (float, [B][6]) at byte offset 707584

#define XS1_STRIDE 296                  // shorts; 592B: 16B-aligned, bank-clean

// ---------------------------------------------------------------------------
// K0: expand conv/FC weights into GEMM-friendly bf16 matrices in ws
// ---------------------------------------------------------------------------
__global__ void k0_build(const float* __restrict__ k1w, const float* __restrict__ k2w,
                         const float* __restrict__ W1, const float* __restrict__ W2,
                         short* __restrict__ ws)
{
    const int NW1 = 1152 * 160, NW2 = 576 * 288, NT1 = 32 * 96, NT2 = 16 * 32;
    const int total = NW1 + NW2 + NT1 + NT2;
    for (int q = blockIdx.x * blockDim.x + threadIdx.x; q < total;
         q += gridDim.x * blockDim.x) {
        float val = 0.f;
        short* dst;
        if (q < NW1) {
            int n = q / 160, kk = q - n * 160;
            dst = ws + WB1_E + q;
            int p1 = n >> 5, r = n & 31;
            int hy = (r >> 4) & 1, hx = (r >> 3) & 1, c = r & 7;
            int yp = p1 / 6, xp = p1 - yp * 6;
            int y = 2 * yp + hy, xo = 2 * xp + hx;
            if (kk < 144) {
                int yi = kk / 12, xi = kk - yi * 12;
                int ky = yi - y + 3, kx = xi - xo + 3;
                if (ky >= 0 && ky < 7 && kx >= 0 && kx < 7)
                    val = k1w[(ky * 7 + kx) * 8 + c];
            }
        } else if (q < NW1 + NW2) {
            int qq = q - NW1;
            int n = qq / 288, k2 = qq - n * 288;
            dst = ws + WB2_E + qq;
            int q2 = n >> 6, r = n & 63, g = r >> 4, c2 = r & 15;
            int gy = g >> 1, gx = g & 1;
            int qy = q2 / 3, qx = q2 - qy * 3;
            int Y = 2 * qy + gy, X = 2 * qx + gx;
            int p1 = k2 >> 3, c1 = k2 & 7;
            int yp = p1 / 6, xp = p1 - yp * 6;
            int ky = yp - Y + 2, kx = xp - X + 2;
            if (c2 < 10 && ky >= 0 && ky < 5 && kx >= 0 && kx < 5)
                val = k2w[((ky * 5 + kx) * 8 + c1) * 10 + c2];
        } else if (q < NW1 + NW2 + NT1) {
            int qq = q - NW1 - NW2;
            int j = qq / 96, k = qq - j * 96;
            dst = ws + W1T_E + qq;
            if (k < 90) val = W1[k * 32 + j];
        } else {
            int qq = q - NW1 - NW2 - NT1;
            int t = qq / 32, k = qq - t * 32;
            dst = ws + W2T_E + qq;
            if (t < 6) val = W2[k * 6 + t];
        }
        *dst = f2bf(val);
    }
}

// ---------------------------------------------------------------------------
// K12: GEMM1 (x @ Wbig1, pool+relu -> xs1 in LDS) + GEMM2 (+pool+relu)
//      + FC1 + FC2 -> theta[B][6] in ws.  xs1 never touches HBM.
//      512 thr = 8 waves, 128 images/block.
//      GEMM2: wave w owns q2=w (ms=8) + its 16-row slice of q2=8 (balanced).
// ---------------------------------------------------------------------------
__global__ __launch_bounds__(512) void k12_gemm(
    const float* __restrict__ x, const short* __restrict__ wb1,
    const short* __restrict__ wb2, const short* __restrict__ w1t,
    const short* __restrict__ w2t, const float* __restrict__ bc1,
    const float* __restrict__ bc2, const float* __restrict__ b1,
    const float* __restrict__ b2, float* __restrict__ theta, int B)
{
    __shared__ short xs1L[128 * XS1_STRIDE];  // 75.8 KB
    __shared__ short XS2[128 * 128];          // 32 KB, XOR-swizzled
    __shared__ short FC1[128 * 64];           // 16 KB, XOR-swizzled

    const int tid = threadIdx.x;
    const int l = tid & 63, w = tid >> 6;     // 8 waves
    const int mg = w >> 2, ng = w & 3;        // GEMM1: 2 Mgrp x 4 Ngrp
    const int lr = l & 15, lg = l >> 4;
    const long long blkbase = (long long)blockIdx.x * 128;
    const int mloc = mg * 64;                 // GEMM1 wave image base

    // zero XS2 pad (cols 90..127 must be 0 for FC1)
    for (int q = tid; q < 2048; q += 512) {
        bfrag z = {0, 0, 0, 0, 0, 0, 0, 0};
        *(bfrag*)&XS2[q * 8] = z;
    }

    // ---- GEMM1: A fragments from global x (f32 -> bf16, registers) ----
    bfrag a[4][5];
    #pragma unroll
    for (int ms = 0; ms < 4; ++ms) {
        long long img = blkbase + mloc + ms * 16 + lr;
        if (img >= B) img = B - 1;
        const float* row = x + (size_t)img * 144;
        #pragma unroll
        for (int t = 0; t < 5; ++t) {
            const int k = t * 32 + lg * 8;
            bfrag f = {0, 0, 0, 0, 0, 0, 0, 0};
            if (k < 144) {
                float4 u0 = *(const float4*)(row + k);
                float4 u1 = *(const float4*)(row + k + 4);
                f[0] = f2bf(u0.x); f[1] = f2bf(u0.y);
                f[2] = f2bf(u0.z); f[3] = f2bf(u0.w);
                f[4] = f2bf(u1.x); f[5] = f2bf(u1.y);
                f[6] = f2bf(u1.z); f[7] = f2bf(u1.w);
            }
            a[ms][t] = f;
        }
    }
    const float bcv = bc1[l & 7];

    auto loadB1 = [&](bfrag (&bb)[2][5], int p1v) {
        const short* p = wb1 + (size_t)(p1v * 32 + lr) * 160 + lg * 8;
        #pragma unroll
        for (int nt = 0; nt < 2; ++nt)
            #pragma unroll
            for (int t = 0; t < 5; ++t)
                bb[nt][t] = *(const bfrag*)(p + (size_t)nt * 16 * 160 + t * 32);
    };
    auto compute1 = [&](bfrag (&bb)[2][5], int p1v) {
        facc acc[4][2];
        #pragma unroll
        for (int ms = 0; ms < 4; ++ms)
            #pragma unroll
            for (int nt = 0; nt < 2; ++nt)
                acc[ms][nt] = (facc){0.f, 0.f, 0.f, 0.f};
        #pragma unroll
        for (int t = 0; t < 5; ++t)
            #pragma unroll
            for (int nt = 0; nt < 2; ++nt)
                #pragma unroll
                for (int ms = 0; ms < 4; ++ms)
                    acc[ms][nt] = mfma16(a[ms][t], bb[nt][t], acc[ms][nt]);
        // pool (nt pools hy; DPP ror8 pools hx) + bias + relu + store
        #pragma unroll
        for (int ms = 0; ms < 4; ++ms)
            #pragma unroll
            for (int i = 0; i < 4; ++i) {
                float p = fmaxf(acc[ms][0][i], acc[ms][1][i]);
                p = maxpair8(p);
                p = fmaxf(p + bcv, 0.f);
                if ((l & 15) < 8) {
                    int mi = mloc + ms * 16 + lg * 4 + i;
                    xs1L[mi * XS1_STRIDE + p1v * 8 + (l & 7)] = f2bf(p);
                }
            }
    };

    {
        bfrag c0[2][5], c1[2][5];
        loadB1(c0, ng);
        #pragma unroll 1
        for (int jp = 0; jp < 4; ++jp) {
            loadB1(c1, (2 * jp + 1) * 4 + ng);
            compute1(c0, (2 * jp) * 4 + ng);
            loadB1(c0, (2 * jp + 2) * 4 + ng);
            compute1(c1, (2 * jp + 1) * 4 + ng);
        }
        compute1(c0, 32 + ng);
    }
    __syncthreads();

    // ---- GEMM2: xs1L @ Wbig2, pool over g, bias+relu -> XS2 ----
    // wave w: q2 = w over all 128 rows (ms=8) + 16-row slice (rows w*16..)
    // of q2 = 8.  324 MFMA per wave, balanced.
    const int c2 = lr;
    const float bcv2 = (c2 < 10) ? bc2[c2] : 0.f;

    auto loadB2 = [&](bfrag (&bb)[4], int q2v, int tv) {
        #pragma unroll
        for (int g = 0; g < 4; ++g)
            bb[g] = *(const bfrag*)(
                wb2 + (size_t)(q2v * 64 + g * 16 + lr) * 288 + tv * 32 + lg * 8);
    };

    {
        const int q2 = w;
        facc acc[8][4];
        facc acc8[4];
        #pragma unroll
        for (int ms = 0; ms < 8; ++ms)
            #pragma unroll
            for (int g = 0; g < 4; ++g)
                acc[ms][g] = (facc){0.f, 0.f, 0.f, 0.f};
        #pragma unroll
        for (int g = 0; g < 4; ++g)
            acc8[g] = (facc){0.f, 0.f, 0.f, 0.f};

        auto mstep = [&](bfrag (&bb)[4], bfrag (&ee)[4], int tv) {
            bfrag av[8];
            #pragma unroll
            for (int ms = 0; ms < 8; ++ms) {
                int m = ms * 16 + lr;
                av[ms] = *(const bfrag*)&xs1L[m * XS1_STRIDE + tv * 32 + lg * 8];
            }
            bfrag av8 = *(const bfrag*)&xs1L[(w * 16 + lr) * XS1_STRIDE + tv * 32 + lg * 8];
            __builtin_amdgcn_s_setprio(1);
            #pragma unroll
            for (int g = 0; g < 4; ++g)
                #pragma unroll
                for (int ms = 0; ms < 8; ++ms)
                    acc[ms][g] = mfma16(av[ms], bb[g], acc[ms][g]);
            #pragma unroll
            for (int g = 0; g < 4; ++g)
                acc8[g] = mfma16(av8, ee[g], acc8[g]);
            __builtin_amdgcn_s_setprio(0);
        };

        bfrag d0[4], d1[4], e0[4], e1[4];
        loadB2(d0, q2, 0); loadB2(e0, 8, 0);
        #pragma unroll 1
        for (int tp = 0; tp < 4; ++tp) {
            loadB2(d1, q2, 2 * tp + 1); loadB2(e1, 8, 2 * tp + 1);
            mstep(d0, e0, 2 * tp);
            loadB2(d0, q2, 2 * tp + 2); loadB2(e0, 8, 2 * tp + 2);
            mstep(d1, e1, 2 * tp + 1);
        }
        mstep(d0, e0, 8);

        // main epilogue: q2 = w columns
        #pragma unroll
        for (int ms = 0; ms < 8; ++ms)
            #pragma unroll
            for (int i = 0; i < 4; ++i) {
                float v = fmaxf(fmaxf(acc[ms][0][i], acc[ms][1][i]),
                                fmaxf(acc[ms][2][i], acc[ms][3][i]));
                v = fmaxf(v + bcv2, 0.f);
                if (c2 < 10) {
                    int mi = ms * 16 + lg * 4 + i;
                    int k = q2 * 10 + c2;
                    XS2[mi * 128 + (((k >> 3) ^ (mi & 7)) << 3) + (k & 7)] = f2bf(v);
                }
            }
        // q2 = 8 slice epilogue: rows w*16..w*16+15, cols 80..89
        #pragma unroll
        for (int i = 0; i < 4; ++i) {
            float v = fmaxf(fmaxf(acc8[0][i], acc8[1][i]),
                            fmaxf(acc8[2][i], acc8[3][i]));
            v = fmaxf(v + bcv2, 0.f);
            if (c2 < 10) {
                int mi = w * 16 + lg * 4 + i;
                int k = 80 + c2;
                XS2[mi * 128 + (((k >> 3) ^ (mi & 7)) << 3) + (k & 7)] = f2bf(v);
            }
        }
    }
    __syncthreads();

    // ---- FC1: relu(xs2 @ W1 + b1) -> FC1 lds (4 mgrp x 2 ngrp, ms=2) ----
    {
        const int mg2 = w >> 1, nt = w & 1;
        facc acc[2];
        acc[0] = (facc){0.f, 0.f, 0.f, 0.f};
        acc[1] = (facc){0.f, 0.f, 0.f, 0.f};
        #pragma unroll
        for (int t = 0; t < 3; ++t) {
            const bfrag bv = *(const bfrag*)(w1t + (size_t)(nt * 16 + lr) * 96 + t * 32 + lg * 8);
            #pragma unroll
            for (int ms = 0; ms < 2; ++ms) {
                int m = mg2 * 32 + ms * 16 + lr;
                bfrag av = *(const bfrag*)&XS2[m * 128 + (((t * 4 + lg) ^ (m & 7)) << 3)];
                acc[ms] = mfma16(av, bv, acc[ms]);
            }
        }
        const int jcol = nt * 16 + lr;
        const float bj = b1[jcol];
        #pragma unroll
        for (int ms = 0; ms < 2; ++ms)
            #pragma unroll
            for (int i = 0; i < 4; ++i) {
                float v = fmaxf(acc[ms][i] + bj, 0.f);
                int mi = mg2 * 32 + ms * 16 + lg * 4 + i;
                FC1[mi * 64 + (((jcol >> 3) ^ (mi & 7)) << 3) + (jcol & 7)] = f2bf(v);
            }
    }
    __syncthreads();

    // ---- FC2: theta = (fc1 @ W2 + b2) / (1+1e-5) -> global ws ----
    if (w < 4) {
        facc acc[2];
        acc[0] = (facc){0.f, 0.f, 0.f, 0.f};
        acc[1] = (facc){0.f, 0.f, 0.f, 0.f};
        const bfrag bv = *(const bfrag*)(w2t + (size_t)lr * 32 + lg * 8);
        #pragma unroll
        for (int ms = 0; ms < 2; ++ms) {
            int m = w * 32 + ms * 16 + lr;
            bfrag av = *(const bfrag*)&FC1[m * 64 + ((lg ^ (m & 7)) << 3)];
            acc[ms] = mfma16(av, bv, acc[ms]);
        }
        if (lr < 6) {
            const float tb = b2[lr];
            const float inv = 1.0f / (1.0f + 1e-5f);
            #pragma unroll
            for (int ms = 0; ms < 2; ++ms)
                #pragma unroll
                for (int i = 0; i < 4; ++i) {
                    long long img = blkbase + w * 32 + ms * 16 + lg * 4 + i;
                    if (img < B) theta[img * 6 + lr] = (acc[ms][i] + tb) * inv;
                }
        }
    }
}

// ---------------------------------------------------------------------------
// K3: affine grid + bilinear sample; 64 images staged in LDS per block
// ---------------------------------------------------------------------------
__global__ __launch_bounds__(256) void k3_sample(
    const float* __restrict__ x, const float* __restrict__ theta,
    float* __restrict__ out, int B)
{
    __shared__ float xL[64 * 145];
    __shared__ float thL[64 * 6];
    const int tid = threadIdx.x;
    const long long blkbase = (long long)blockIdx.x * 64;

    const float4* xg4 = (const float4*)(x + blkbase * 144);
    for (int q = tid; q < 2304; q += 256) {
        int il = q / 36, c4 = q - il * 36;
        float4 v = make_float4(0.f, 0.f, 0.f, 0.f);
        if (blkbase + il < B) v = xg4[(size_t)il * 36 + c4];
        *(float4*)&xL[il * 145 + c4 * 4] = v;
    }
    for (int q = tid; q < 384; q += 256) {
        long long idx = blkbase * 6 + q;
        if (idx < (long long)B * 6) thL[q] = theta[idx];
    }
    __syncthreads();

    const int il = tid >> 2, quad = tid & 3;
    const long long img = blkbase + il;
    if (img >= B) return;

    const float t0 = thL[il * 6 + 0];
    const float t1 = thL[il * 6 + 1];
    const float t2 = thL[il * 6 + 2];
    const float t3 = thL[il * 6 + 3];
    const float t4 = thL[il * 6 + 4];
    const float t5 = thL[il * 6 + 5];
    const float* xr = &xL[il * 145];
    const float step = 2.0f / 11.0f;
    const float t0s = t0 * 5.5f, t3s = t3 * 5.5f;

    float o[36];
    #pragma unroll
    for (int rr = 0; rr < 3; ++rr) {
        const int iy = quad * 3 + rr;
        const float yn = -1.0f + iy * step;
        const float cx = (t1 * yn + t2 + 1.0f) * 5.5f;
        const float cy = (t4 * yn + t5 + 1.0f) * 5.5f;
        #pragma unroll
        for (int jx = 0; jx < 12; ++jx) {
            const float xn = -1.0f + jx * step;
            const float px = fmaf(t0s, xn, cx);
            const float py = fmaf(t3s, xn, cy);
            const float fy = floorf(py), fx = floorf(px);
            const float wy = py - fy,    wx = px - fx;
            const int ly = (int)fy, lx = (int)fx;
            const int y0 = refl12(ly), y1 = refl12(ly + 1);
            const int x0 = refl12(lx), x1 = refl12(lx + 1);
            const float v00 = xr[y0 * 12 + x0];
            const float v01 = xr[y0 * 12 + x1];
            const float v10 = xr[y1 * 12 + x0];
            const float v11 = xr[y1 * 12 + x1];
            const float r0 = v00 + wx * (v01 - v00);
            const float r1 = v10 + wx * (v11 - v10);
            o[rr * 12 + jx] = r0 + wy * (r1 - r0);
        }
    }
    float* op = out + (size_t)img * 144 + quad * 36;
    #pragma unroll
    for (int k = 0; k < 9; ++k)
        *(float4*)(op + 4 * k) = make_float4(o[4*k], o[4*k+1], o[4*k+2], o[4*k+3]);
}

extern "C" void kernel_launch(void* const* d_in, const int* in_sizes, int n_in,
                              void* d_out, int out_size, void* d_ws, size_t ws_size,
                              hipStream_t stream)
{
    const float* x   = (const float*)d_in[0];
    const float* k1w = (const float*)d_in[1];
    const float* bc1 = (const float*)d_in[2];
    const float* k2w = (const float*)d_in[3];
    const float* bc2 = (const float*)d_in[4];
    const float* W1  = (const float*)d_in[5];
    const float* b1  = (const float*)d_in[6];
    const float* W2  = (const float*)d_in[7];
    const float* b2  = (const float*)d_in[8];
    float* out = (float*)d_out;
    const int B = in_sizes[0] / 144;

    short* ws = (short*)d_ws;
    short* wb1 = ws + WB1_E;
    short* wb2 = ws + WB2_E;
    short* w1t = ws + W1T_E;
    short* w2t = ws + W2T_E;
    float* theta = (float*)((char*)d_ws + 707584);

    hipLaunchKernelGGL(k0_build, dim3(512), dim3(256), 0, stream,
                       k1w, k2w, W1, W2, ws);

    const int nb = (B + 127) / 128;
    hipLaunchKernelGGL(k12_gemm, dim3(nb), dim3(512), 0, stream,
                       x, wb1, wb2, w1t, w2t, bc1, bc2, b1, b2, theta, B);

    const int nb3 = (int)((B + 63) / 64);
    hipLaunchKernelGGL(k3_sample, dim3(nb3), dim3(256), 0, stream,
                       x, theta, out, B);
}

// Round 13
// 172.092 us; speedup vs baseline: 1.4267x; 1.2305x over previous
//
#include <hip/hip_runtime.h>

typedef __attribute__((ext_vector_type(8))) short bfrag;   // 8 x bf16
typedef __attribute__((ext_vector_type(4))) float facc;    // mfma accumulator

__device__ __forceinline__ short f2bf(float f) {
    unsigned u = __float_as_uint(f);
    u += 0x7FFFu + ((u >> 16) & 1u);          // round-to-nearest-even
    return (short)(u >> 16);
}
__device__ __forceinline__ float maxpair8(float p) {
    // max(p[lane], p[lane^8]) within 16-lane rows; row_ror:8 == xor 8 (mod 16).
    // Intrinsic DPP -> compiler handles hazards (r12 correctness-verified).
    int r = __builtin_amdgcn_update_dpp(0, __float_as_int(p),
                                        0x128 /*row_ror:8*/, 0xf, 0xf, true);
    return fmaxf(p, __int_as_float(r));
}
__device__ __forceinline__ int refl12(int i) {
    int r = i % 24; if (r < 0) r += 24; return (r < 12) ? r : 23 - r;
}
__device__ __forceinline__ facc mfma16(bfrag a, bfrag b, facc c) {
    return __builtin_amdgcn_mfma_f32_16x16x32_bf16(a, b, c, 0, 0, 0);
}

// ws layout (element offsets in shorts)
#define WB1_E 0                         // [1152][160] bf16
#define WB2_E 184320                    // [576][288]  bf16
#define W1T_E 350208                    // [32][96]    bf16
#define W2T_E 353280                    // [16][32]    bf16
// theta (float, [B][6]) at byte offset 707584

#define XS1_STRIDE 296                  // shorts; 592B: 16B-aligned, bank-clean

// ---------------------------------------------------------------------------
// K0: expand conv/FC weights into GEMM-friendly bf16 matrices in ws
// ---------------------------------------------------------------------------
__global__ void k0_build(const float* __restrict__ k1w, const float* __restrict__ k2w,
                         const float* __restrict__ W1, const float* __restrict__ W2,
                         short* __restrict__ ws)
{
    const int NW1 = 1152 * 160, NW2 = 576 * 288, NT1 = 32 * 96, NT2 = 16 * 32;
    const int total = NW1 + NW2 + NT1 + NT2;
    for (int q = blockIdx.x * blockDim.x + threadIdx.x; q < total;
         q += gridDim.x * blockDim.x) {
        float val = 0.f;
        short* dst;
        if (q < NW1) {
            int n = q / 160, kk = q - n * 160;
            dst = ws + WB1_E + q;
            int p1 = n >> 5, r = n & 31;
            int hy = (r >> 4) & 1, hx = (r >> 3) & 1, c = r & 7;
            int yp = p1 / 6, xp = p1 - yp * 6;
            int y = 2 * yp + hy, xo = 2 * xp + hx;
            if (kk < 144) {
                int yi = kk / 12, xi = kk - yi * 12;
                int ky = yi - y + 3, kx = xi - xo + 3;
                if (ky >= 0 && ky < 7 && kx >= 0 && kx < 7)
                    val = k1w[(ky * 7 + kx) * 8 + c];
            }
        } else if (q < NW1 + NW2) {
            int qq = q - NW1;
            int n = qq / 288, k2 = qq - n * 288;
            dst = ws + WB2_E + qq;
            int q2 = n >> 6, r = n & 63, g = r >> 4, c2 = r & 15;
            int gy = g >> 1, gx = g & 1;
            int qy = q2 / 3, qx = q2 - qy * 3;
            int Y = 2 * qy + gy, X = 2 * qx + gx;
            int p1 = k2 >> 3, c1 = k2 & 7;
            int yp = p1 / 6, xp = p1 - yp * 6;
            int ky = yp - Y + 2, kx = xp - X + 2;
            if (c2 < 10 && ky >= 0 && ky < 5 && kx >= 0 && kx < 5)
                val = k2w[((ky * 5 + kx) * 8 + c1) * 10 + c2];
        } else if (q < NW1 + NW2 + NT1) {
            int qq = q - NW1 - NW2;
            int j = qq / 96, k = qq - j * 96;
            dst = ws + W1T_E + qq;
            if (k < 90) val = W1[k * 32 + j];
        } else {
            int qq = q - NW1 - NW2 - NT1;
            int t = qq / 32, k = qq - t * 32;
            dst = ws + W2T_E + qq;
            if (t < 6) val = W2[k * 6 + t];
        }
        *dst = f2bf(val);
    }
}

// ---------------------------------------------------------------------------
// K12: GEMM1 (x @ Wbig1, pool+relu -> xs1 in LDS) + GEMM2 (+pool+relu)
//      + FC1 + FC2 -> theta[B][6] in ws.  xs1 never touches HBM.
//      512 thr = 8 waves, 128 images/block (r10 structure).
//      GEMM1: double-acc pipeline — epilogue(j) overlaps MFMA(j+1).
//      GEMM2: wave w owns q2=w (ms=8); q2=8 split over waves 0/1.
// ---------------------------------------------------------------------------
__global__ __launch_bounds__(512) void k12_gemm(
    const float* __restrict__ x, const short* __restrict__ wb1,
    const short* __restrict__ wb2, const short* __restrict__ w1t,
    const short* __restrict__ w2t, const float* __restrict__ bc1,
    const float* __restrict__ bc2, const float* __restrict__ b1,
    const float* __restrict__ b2, float* __restrict__ theta, int B)
{
    __shared__ short xs1L[128 * XS1_STRIDE];  // 75.8 KB
    __shared__ short XS2[128 * 128];          // 32 KB, XOR-swizzled
    __shared__ short FC1[128 * 64];           // 16 KB, XOR-swizzled

    const int tid = threadIdx.x;
    const int l = tid & 63, w = tid >> 6;     // 8 waves
    const int mg = w >> 2, ng = w & 3;        // GEMM1: 2 Mgrp x 4 Ngrp
    const int lr = l & 15, lg = l >> 4;
    const long long blkbase = (long long)blockIdx.x * 128;
    const int mloc = mg * 64;                 // GEMM1 wave image base

    // zero XS2 pad (cols 90..127 must be 0 for FC1)
    for (int q = tid; q < 2048; q += 512) {
        bfrag z = {0, 0, 0, 0, 0, 0, 0, 0};
        *(bfrag*)&XS2[q * 8] = z;
    }

    // ---- GEMM1: A fragments from global x (f32 -> bf16, registers) ----
    bfrag a[4][5];
    #pragma unroll
    for (int ms = 0; ms < 4; ++ms) {
        long long img = blkbase + mloc + ms * 16 + lr;
        if (img >= B) img = B - 1;
        const float* row = x + (size_t)img * 144;
        #pragma unroll
        for (int t = 0; t < 5; ++t) {
            const int k = t * 32 + lg * 8;
            bfrag f = {0, 0, 0, 0, 0, 0, 0, 0};
            if (k < 144) {
                float4 u0 = *(const float4*)(row + k);
                float4 u1 = *(const float4*)(row + k + 4);
                f[0] = f2bf(u0.x); f[1] = f2bf(u0.y);
                f[2] = f2bf(u0.z); f[3] = f2bf(u0.w);
                f[4] = f2bf(u1.x); f[5] = f2bf(u1.y);
                f[6] = f2bf(u1.z); f[7] = f2bf(u1.w);
            }
            a[ms][t] = f;
        }
    }
    const float bcv = bc1[l & 7];

    auto loadB1 = [&](bfrag (&bb)[2][5], int p1v) {
        const short* p = wb1 + (size_t)(p1v * 32 + lr) * 160 + lg * 8;
        #pragma unroll
        for (int nt = 0; nt < 2; ++nt)
            #pragma unroll
            for (int t = 0; t < 5; ++t)
                bb[nt][t] = *(const bfrag*)(p + (size_t)nt * 16 * 160 + t * 32);
    };
    auto mfma1 = [&](bfrag (&bb)[2][5], facc (&acc)[4][2]) {
        #pragma unroll
        for (int ms = 0; ms < 4; ++ms)
            #pragma unroll
            for (int nt = 0; nt < 2; ++nt)
                acc[ms][nt] = (facc){0.f, 0.f, 0.f, 0.f};
        #pragma unroll
        for (int t = 0; t < 5; ++t)
            #pragma unroll
            for (int nt = 0; nt < 2; ++nt)
                #pragma unroll
                for (int ms = 0; ms < 4; ++ms)
                    acc[ms][nt] = mfma16(a[ms][t], bb[nt][t], acc[ms][nt]);
    };
    auto epi1 = [&](facc (&acc)[4][2], int p1v) {
        // pool (nt pools hy; DPP ror8 pools hx) + bias + relu + store
        #pragma unroll
        for (int ms = 0; ms < 4; ++ms)
            #pragma unroll
            for (int i = 0; i < 4; ++i) {
                float p = fmaxf(acc[ms][0][i], acc[ms][1][i]);
                p = maxpair8(p);
                p = fmaxf(p + bcv, 0.f);
                if ((l & 15) < 8) {
                    int mi = mloc + ms * 16 + lg * 4 + i;
                    xs1L[mi * XS1_STRIDE + p1v * 8 + (l & 7)] = f2bf(p);
                }
            }
    };

    {   // chunk c -> p1 = 4c + ng, c = 0..8.  Pipeline: epi(j) under mfma(j+1).
        bfrag c0[2][5], c1[2][5];
        facc accA[4][2], accB[4][2];
        loadB1(c0, ng);
        mfma1(c0, accA);                         // chunk 0
        loadB1(c1, 4 + ng);                      // B chunk 1
        #pragma unroll 1
        for (int jp = 0; jp < 4; ++jp) {
            mfma1(c1, accB);                     // chunk 2jp+1
            loadB1(c0, (2 * jp + 2) * 4 + ng);   // B chunk 2jp+2
            epi1(accA, (2 * jp) * 4 + ng);       // epi chunk 2jp  (|| mfma above)
            mfma1(c0, accA);                     // chunk 2jp+2
            if (jp < 3) loadB1(c1, (2 * jp + 3) * 4 + ng);
            epi1(accB, (2 * jp + 1) * 4 + ng);   // epi chunk 2jp+1
        }
        epi1(accA, 32 + ng);                     // chunk 8
    }
    __syncthreads();

    // ---- GEMM2: xs1L @ Wbig2, pool over g, bias+relu -> XS2 ----
    // wave w owns q2 = w (full M=128, ms=8); q2=8 split: wave0 m0-63, wave1 m64-127
    const int c2 = lr;
    const float bcv2 = (c2 < 10) ? bc2[c2] : 0.f;

    auto loadB2 = [&](bfrag (&bb)[4], int q2v, int tv) {
        #pragma unroll
        for (int g = 0; g < 4; ++g)
            bb[g] = *(const bfrag*)(
                wb2 + (size_t)(q2v * 64 + g * 16 + lr) * 288 + tv * 32 + lg * 8);
    };

    {   // full-tile task: q2 = w, all 8 m-tiles
        const int q2 = w;
        facc acc[8][4];
        #pragma unroll
        for (int ms = 0; ms < 8; ++ms)
            #pragma unroll
            for (int g = 0; g < 4; ++g)
                acc[ms][g] = (facc){0.f, 0.f, 0.f, 0.f};

        auto mstep8 = [&](bfrag (&bb)[4], int tv) {
            bfrag av[8];
            #pragma unroll
            for (int ms = 0; ms < 8; ++ms) {
                int m = ms * 16 + lr;
                av[ms] = *(const bfrag*)&xs1L[m * XS1_STRIDE + tv * 32 + lg * 8];
            }
            __builtin_amdgcn_s_setprio(1);
            #pragma unroll
            for (int g = 0; g < 4; ++g)
                #pragma unroll
                for (int ms = 0; ms < 8; ++ms)
                    acc[ms][g] = mfma16(av[ms], bb[g], acc[ms][g]);
            __builtin_amdgcn_s_setprio(0);
        };

        bfrag d0[4], d1[4];
        loadB2(d0, q2, 0);
        #pragma unroll 1
        for (int tp = 0; tp < 4; ++tp) {
            loadB2(d1, q2, 2 * tp + 1);
            mstep8(d0, 2 * tp);
            loadB2(d0, q2, 2 * tp + 2);
            mstep8(d1, 2 * tp + 1);
        }
        mstep8(d0, 8);

        #pragma unroll
        for (int ms = 0; ms < 8; ++ms)
            #pragma unroll
            for (int i = 0; i < 4; ++i) {
                float v = fmaxf(fmaxf(acc[ms][0][i], acc[ms][1][i]),
                                fmaxf(acc[ms][2][i], acc[ms][3][i]));
                v = fmaxf(v + bcv2, 0.f);
                if (c2 < 10) {
                    int mi = ms * 16 + lg * 4 + i;
                    int k = q2 * 10 + c2;
                    XS2[mi * 128 + (((k >> 3) ^ (mi & 7)) << 3) + (k & 7)] = f2bf(v);
                }
            }
    }

    if (w < 2) {   // half-tile task: q2 = 8, m-half per wave
        const int q2 = 8;
        const int mBase = w * 64;
        facc acc[4][4];
        #pragma unroll
        for (int ms = 0; ms < 4; ++ms)
            #pragma unroll
            for (int g = 0; g < 4; ++g)
                acc[ms][g] = (facc){0.f, 0.f, 0.f, 0.f};

        auto mstep4 = [&](bfrag (&bb)[4], int tv) {
            bfrag av[4];
            #pragma unroll
            for (int ms = 0; ms < 4; ++ms) {
                int m = mBase + ms * 16 + lr;
                av[ms] = *(const bfrag*)&xs1L[m * XS1_STRIDE + tv * 32 + lg * 8];
            }
            __builtin_amdgcn_s_setprio(1);
            #pragma unroll
            for (int g = 0; g < 4; ++g)
                #pragma unroll
                for (int ms = 0; ms < 4; ++ms)
                    acc[ms][g] = mfma16(av[ms], bb[g], acc[ms][g]);
            __builtin_amdgcn_s_setprio(0);
        };

        bfrag d0[4], d1[4];
        loadB2(d0, q2, 0);
        #pragma unroll 1
        for (int tp = 0; tp < 4; ++tp) {
            loadB2(d1, q2, 2 * tp + 1);
            mstep4(d0, 2 * tp);
            loadB2(d0, q2, 2 * tp + 2);
            mstep4(d1, 2 * tp + 1);
        }
        mstep4(d0, 8);

        #pragma unroll
        for (int ms = 0; ms < 4; ++ms)
            #pragma unroll
            for (int i = 0; i < 4; ++i) {
                float v = fmaxf(fmaxf(acc[ms][0][i], acc[ms][1][i]),
                                fmaxf(acc[ms][2][i], acc[ms][3][i]));
                v = fmaxf(v + bcv2, 0.f);
                if (c2 < 10) {
                    int mi = mBase + ms * 16 + lg * 4 + i;
                    int k = q2 * 10 + c2;
                    XS2[mi * 128 + (((k >> 3) ^ (mi & 7)) << 3) + (k & 7)] = f2bf(v);
                }
            }
    }
    __syncthreads();

    // ---- FC1: relu(xs2 @ W1 + b1) -> FC1 lds (4 mgrp x 2 ngrp, ms=2) ----
    {
        const int mg2 = w >> 1, nt = w & 1;
        facc acc[2];
        acc[0] = (facc){0.f, 0.f, 0.f, 0.f};
        acc[1] = (facc){0.f, 0.f, 0.f, 0.f};
        #pragma unroll
        for (int t = 0; t < 3; ++t) {
            const bfrag bv = *(const bfrag*)(w1t + (size_t)(nt * 16 + lr) * 96 + t * 32 + lg * 8);
            #pragma unroll
            for (int ms = 0; ms < 2; ++ms) {
                int m = mg2 * 32 + ms * 16 + lr;
                bfrag av = *(const bfrag*)&XS2[m * 128 + (((t * 4 + lg) ^ (m & 7)) << 3)];
                acc[ms] = mfma16(av, bv, acc[ms]);
            }
        }
        const int jcol = nt * 16 + lr;
        const float bj = b1[jcol];
        #pragma unroll
        for (int ms = 0; ms < 2; ++ms)
            #pragma unroll
            for (int i = 0; i < 4; ++i) {
                float v = fmaxf(acc[ms][i] + bj, 0.f);
                int mi = mg2 * 32 + ms * 16 + lg * 4 + i;
                FC1[mi * 64 + (((jcol >> 3) ^ (mi & 7)) << 3) + (jcol & 7)] = f2bf(v);
            }
    }
    __syncthreads();

    // ---- FC2: theta = (fc1 @ W2 + b2) / (1+1e-5) -> global ws ----
    if (w < 4) {
        facc acc[2];
        acc[0] = (facc){0.f, 0.f, 0.f, 0.f};
        acc[1] = (facc){0.f, 0.f, 0.f, 0.f};
        const bfrag bv = *(const bfrag*)(w2t + (size_t)lr * 32 + lg * 8);
        #pragma unroll
        for (int ms = 0; ms < 2; ++ms) {
            int m = w * 32 + ms * 16 + lr;
            bfrag av = *(const bfrag*)&FC1[m * 64 + ((lg ^ (m & 7)) << 3)];
            acc[ms] = mfma16(av, bv, acc[ms]);
        }
        if (lr < 6) {
            const float tb = b2[lr];
            const float inv = 1.0f / (1.0f + 1e-5f);
            #pragma unroll
            for (int ms = 0; ms < 2; ++ms)
                #pragma unroll
                for (int i = 0; i < 4; ++i) {
                    long long img = blkbase + w * 32 + ms * 16 + lg * 4 + i;
                    if (img < B) theta[img * 6 + lr] = (acc[ms][i] + tb) * inv;
                }
        }
    }
}

// ---------------------------------------------------------------------------
// K3: affine grid + bilinear sample; 64 images staged in LDS per block
// ---------------------------------------------------------------------------
__global__ __launch_bounds__(256) void k3_sample(
    const float* __restrict__ x, const float* __restrict__ theta,
    float* __restrict__ out, int B)
{
    __shared__ float xL[64 * 145];
    __shared__ float thL[64 * 6];
    const int tid = threadIdx.x;
    const long long blkbase = (long long)blockIdx.x * 64;

    const float4* xg4 = (const float4*)(x + blkbase * 144);
    for (int q = tid; q < 2304; q += 256) {
        int il = q / 36, c4 = q - il * 36;
        float4 v = make_float4(0.f, 0.f, 0.f, 0.f);
        if (blkbase + il < B) v = xg4[(size_t)il * 36 + c4];
        *(float4*)&xL[il * 145 + c4 * 4] = v;
    }
    for (int q = tid; q < 384; q += 256) {
        long long idx = blkbase * 6 + q;
        if (idx < (long long)B * 6) thL[q] = theta[idx];
    }
    __syncthreads();

    const int il = tid >> 2, quad = tid & 3;
    const long long img = blkbase + il;
    if (img >= B) return;

    const float t0 = thL[il * 6 + 0];
    const float t1 = thL[il * 6 + 1];
    const float t2 = thL[il * 6 + 2];
    const float t3 = thL[il * 6 + 3];
    const float t4 = thL[il * 6 + 4];
    const float t5 = thL[il * 6 + 5];
    const float* xr = &xL[il * 145];
    const float step = 2.0f / 11.0f;
    const float t0s = t0 * 5.5f, t3s = t3 * 5.5f;

    float o[36];
    #pragma unroll
    for (int rr = 0; rr < 3; ++rr) {
        const int iy = quad * 3 + rr;
        const float yn = -1.0f + iy * step;
        const float cx = (t1 * yn + t2 + 1.0f) * 5.5f;
        const float cy = (t4 * yn + t5 + 1.0f) * 5.5f;
        #pragma unroll
        for (int jx = 0; jx < 12; ++jx) {
            const float xn = -1.0f + jx * step;
            const float px = fmaf(t0s, xn, cx);
            const float py = fmaf(t3s, xn, cy);
            const float fy = floorf(py), fx = floorf(px);
            const float wy = py - fy,    wx = px - fx;
            const int ly = (int)fy, lx = (int)fx;
            const int y0 = refl12(ly), y1 = refl12(ly + 1);
            const int x0 = refl12(lx), x1 = refl12(lx + 1);
            const float v00 = xr[y0 * 12 + x0];
            const float v01 = xr[y0 * 12 + x1];
            const float v10 = xr[y1 * 12 + x0];
            const float v11 = xr[y1 * 12 + x1];
            const float r0 = v00 + wx * (v01 - v00);
            const float r1 = v10 + wx * (v11 - v10);
            o[rr * 12 + jx] = r0 + wy * (r1 - r0);
        }
    }
    float* op = out + (size_t)img * 144 + quad * 36;
    #pragma unroll
    for (int k = 0; k < 9; ++k)
        *(float4*)(op + 4 * k) = make_float4(o[4*k], o[4*k+1], o[4*k+2], o[4*k+3]);
}

extern "C" void kernel_launch(void* const* d_in, const int* in_sizes, int n_in,
                              void* d_out, int out_size, void* d_ws, size_t ws_size,
                              hipStream_t stream)
{
    const float* x   = (const float*)d_in[0];
    const float* k1w = (const float*)d_in[1];
    const float* bc1 = (const float*)d_in[2];
    const float* k2w = (const float*)d_in[3];
    const float* bc2 = (const float*)d_in[4];
    const float* W1  = (const float*)d_in[5];
    const float* b1  = (const float*)d_in[6];
    const float* W2  = (const float*)d_in[7];
    const float* b2  = (const float*)d_in[8];
    float* out = (float*)d_out;
    const int B = in_sizes[0] / 144;

    short* ws = (short*)d_ws;
    short* wb1 = ws + WB1_E;
    short* wb2 = ws + WB2_E;
    short* w1t = ws + W1T_E;
    short* w2t = ws + W2T_E;
    float* theta = (float*)((char*)d_ws + 707584);

    hipLaunchKernelGGL(k0_build, dim3(512), dim3(256), 0, stream,
                       k1w, k2w, W1, W2, ws);

    const int nb = (B + 127) / 128;
    hipLaunchKernelGGL(k12_gemm, dim3(nb), dim3(512), 0, stream,
                       x, wb1, wb2, w1t, w2t, bc1, bc2, b1, b2, theta, B);

    const int nb3 = (int)((B + 63) / 64);
    hipLaunchKernelGGL(k3_sample, dim3(nb3), dim3(256), 0, stream,
                       x, theta, out, B);
}

// Round 14
// 168.021 us; speedup vs baseline: 1.4613x; 1.0242x over previous
//
#include <hip/hip_runtime.h>

typedef __attribute__((ext_vector_type(8))) short bfrag;   // 8 x bf16
typedef __attribute__((ext_vector_type(4))) float facc;    // mfma accumulator

__device__ __forceinline__ short f2bf(float f) {
    unsigned u = __float_as_uint(f);
    u += 0x7FFFu + ((u >> 16) & 1u);          // round-to-nearest-even
    return (short)(u >> 16);
}
__device__ __forceinline__ float maxpair8(float p) {
    // max(p[lane], p[lane^8]) within 16-lane rows; row_ror:8 == xor 8 (mod 16).
    int r = __builtin_amdgcn_update_dpp(0, __float_as_int(p),
                                        0x128 /*row_ror:8*/, 0xf, 0xf, true);
    return fmaxf(p, __int_as_float(r));
}
__device__ __forceinline__ int refl12(int i) {
    int r = i % 24; if (r < 0) r += 24; return (r < 12) ? r : 23 - r;
}
__device__ __forceinline__ facc mfma16(bfrag a, bfrag b, facc c) {
    return __builtin_amdgcn_mfma_f32_16x16x32_bf16(a, b, c, 0, 0, 0);
}

// ws layout (element offsets in shorts)
#define WB1_E 0                         // [1152][160] bf16  (col 144 = bias)
#define WB2_E 184320                    // [576][288]  bf16
#define W1T_E 350208                    // [32][96]    bf16
#define W2T_E 353280                    // [16][32]    bf16
// theta (float, [B][6]) at byte offset 707584

#define XS1_STRIDE 296                  // shorts; 592B: 16B-aligned, bank-clean

// ---------------------------------------------------------------------------
// K0: expand conv/FC weights into GEMM-friendly bf16 matrices in ws
// ---------------------------------------------------------------------------
__global__ void k0_build(const float* __restrict__ k1w, const float* __restrict__ bc1,
                         const float* __restrict__ k2w,
                         const float* __restrict__ W1, const float* __restrict__ W2,
                         short* __restrict__ ws)
{
    const int NW1 = 1152 * 160, NW2 = 576 * 288, NT1 = 32 * 96, NT2 = 16 * 32;
    const int total = NW1 + NW2 + NT1 + NT2;
    for (int q = blockIdx.x * blockDim.x + threadIdx.x; q < total;
         q += gridDim.x * blockDim.x) {
        float val = 0.f;
        short* dst;
        if (q < NW1) {
            int n = q / 160, kk = q - n * 160;
            dst = ws + WB1_E + q;
            int p1 = n >> 5, r = n & 31;
            int hy = (r >> 4) & 1, hx = (r >> 3) & 1, c = r & 7;
            int yp = p1 / 6, xp = p1 - yp * 6;
            int y = 2 * yp + hy, xo = 2 * xp + hx;
            if (kk < 144) {
                int yi = kk / 12, xi = kk - yi * 12;
                int ky = yi - y + 3, kx = xi - xo + 3;
                if (ky >= 0 && ky < 7 && kx >= 0 && kx < 7)
                    val = k1w[(ky * 7 + kx) * 8 + c];
            } else if (kk == 144) {
                val = bc1[c];                 // bias folded into K (A[144] = 1)
            }
        } else if (q < NW1 + NW2) {
            int qq = q - NW1;
            int n = qq / 288, k2 = qq - n * 288;
            dst = ws + WB2_E + qq;
            int q2 = n >> 6, r = n & 63, g = r >> 4, c2 = r & 15;
            int gy = g >> 1, gx = g & 1;
            int qy = q2 / 3, qx = q2 - qy * 3;
            int Y = 2 * qy + gy, X = 2 * qx + gx;
            int p1 = k2 >> 3, c1 = k2 & 7;
            int yp = p1 / 6, xp = p1 - yp * 6;
            int ky = yp - Y + 2, kx = xp - X + 2;
            if (c2 < 10 && ky >= 0 && ky < 5 && kx >= 0 && kx < 5)
                val = k2w[((ky * 5 + kx) * 8 + c1) * 10 + c2];
        } else if (q < NW1 + NW2 + NT1) {
            int qq = q - NW1 - NW2;
            int j = qq / 96, k = qq - j * 96;
            dst = ws + W1T_E + qq;
            if (k < 90) val = W1[k * 32 + j];
        } else {
            int qq = q - NW1 - NW2 - NT1;
            int t = qq / 32, k = qq - t * 32;
            dst = ws + W2T_E + qq;
            if (t < 6) val = W2[k * 6 + t];
        }
        *dst = f2bf(val);
    }
}

// ---------------------------------------------------------------------------
// K12: GEMM1 (x @ Wbig1, pool+relu -> xs1 in LDS) + GEMM2 (+pool+relu)
//      + FC1 + FC2 -> theta[B][6] in ws.  xs1 never touches HBM.
//      512 thr = 8 waves, 128 images/block.
//      GEMM1: double-acc pipeline, bias-in-K.  Pre-barrier B prefetch.
//      GEMM2: wave w owns q2=w (ms=8); q2=8 split over waves 0/1.
// ---------------------------------------------------------------------------
__global__ __launch_bounds__(512) void k12_gemm(
    const float* __restrict__ x, const short* __restrict__ wb1,
    const short* __restrict__ wb2, const short* __restrict__ w1t,
    const short* __restrict__ w2t, const float* __restrict__ bc2,
    const float* __restrict__ b1, const float* __restrict__ b2,
    float* __restrict__ theta, int B)
{
    __shared__ short xs1L[128 * XS1_STRIDE];  // 75.8 KB
    __shared__ short XS2[128 * 128];          // 32 KB, XOR-swizzled
    __shared__ short FC1[128 * 64];           // 16 KB, XOR-swizzled

    const int tid = threadIdx.x;
    const int l = tid & 63, w = tid >> 6;     // 8 waves
    const int mg = w >> 2, ng = w & 3;        // GEMM1: 2 Mgrp x 4 Ngrp
    const int lr = l & 15, lg = l >> 4;
    const long long blkbase = (long long)blockIdx.x * 128;
    const int mloc = mg * 64;                 // GEMM1 wave image base

    // zero XS2 pad (cols 90..127 must be 0 for FC1)
    for (int q = tid; q < 2048; q += 512) {
        bfrag z = {0, 0, 0, 0, 0, 0, 0, 0};
        *(bfrag*)&XS2[q * 8] = z;
    }

    // ---- GEMM1: A fragments from global x (f32 -> bf16, registers) ----
    bfrag a[4][5];
    #pragma unroll
    for (int ms = 0; ms < 4; ++ms) {
        long long img = blkbase + mloc + ms * 16 + lr;
        if (img >= B) img = B - 1;
        const float* row = x + (size_t)img * 144;
        #pragma unroll
        for (int t = 0; t < 5; ++t) {
            const int k = t * 32 + lg * 8;
            bfrag f = {0, 0, 0, 0, 0, 0, 0, 0};
            if (k < 144) {
                float4 u0 = *(const float4*)(row + k);
                float4 u1 = *(const float4*)(row + k + 4);
                f[0] = f2bf(u0.x); f[1] = f2bf(u0.y);
                f[2] = f2bf(u0.z); f[3] = f2bf(u0.w);
                f[4] = f2bf(u1.x); f[5] = f2bf(u1.y);
                f[6] = f2bf(u1.z); f[7] = f2bf(u1.w);
            } else if (k == 144) {
                f[0] = (short)0x3F80;         // 1.0 bf16 -> bias term
            }
            a[ms][t] = f;
        }
    }

    auto loadB1 = [&](bfrag (&bb)[2][5], int p1v) {
        const short* p = wb1 + (size_t)(p1v * 32 + lr) * 160 + lg * 8;
        #pragma unroll
        for (int nt = 0; nt < 2; ++nt)
            #pragma unroll
            for (int t = 0; t < 5; ++t)
                bb[nt][t] = *(const bfrag*)(p + (size_t)nt * 16 * 160 + t * 32);
    };
    auto mfma1 = [&](bfrag (&bb)[2][5], facc (&acc)[4][2]) {
        #pragma unroll
        for (int ms = 0; ms < 4; ++ms)
            #pragma unroll
            for (int nt = 0; nt < 2; ++nt)
                acc[ms][nt] = (facc){0.f, 0.f, 0.f, 0.f};
        #pragma unroll
        for (int t = 0; t < 5; ++t)
            #pragma unroll
            for (int nt = 0; nt < 2; ++nt)
                #pragma unroll
                for (int ms = 0; ms < 4; ++ms)
                    acc[ms][nt] = mfma16(a[ms][t], bb[nt][t], acc[ms][nt]);
    };
    auto epi1 = [&](facc (&acc)[4][2], int p1v) {
        // pool (nt pools hy; DPP ror8 pools hx) + relu + store (bias in K)
        #pragma unroll
        for (int ms = 0; ms < 4; ++ms)
            #pragma unroll
            for (int i = 0; i < 4; ++i) {
                float p = fmaxf(acc[ms][0][i], acc[ms][1][i]);
                p = maxpair8(p);
                p = fmaxf(p, 0.f);
                if ((l & 15) < 8) {
                    int mi = mloc + ms * 16 + lg * 4 + i;
                    xs1L[mi * XS1_STRIDE + p1v * 8 + (l & 7)] = f2bf(p);
                }
            }
    };

    {   // chunk c -> p1 = 4c + ng, c = 0..8.  Pipeline: epi(j) under mfma(j+1).
        bfrag c0[2][5], c1[2][5];
        facc accA[4][2], accB[4][2];
        loadB1(c0, ng);
        mfma1(c0, accA);                         // chunk 0
        loadB1(c1, 4 + ng);                      // B chunk 1
        #pragma unroll 1
        for (int jp = 0; jp < 4; ++jp) {
            mfma1(c1, accB);                     // chunk 2jp+1
            loadB1(c0, (2 * jp + 2) * 4 + ng);   // B chunk 2jp+2
            epi1(accA, (2 * jp) * 4 + ng);       // epi chunk 2jp  (|| mfma above)
            mfma1(c0, accA);                     // chunk 2jp+2
            if (jp < 3) loadB1(c1, (2 * jp + 3) * 4 + ng);
            epi1(accB, (2 * jp + 1) * 4 + ng);   // epi chunk 2jp+1
        }
        epi1(accA, 32 + ng);                     // chunk 8
    }

    // ---- pre-barrier prefetch of GEMM2's first B fragments (global) ----
    const int c2 = lr;
    const float bcv2 = (c2 < 10) ? bc2[c2] : 0.f;

    auto loadB2 = [&](bfrag (&bb)[4], int q2v, int tv) {
        #pragma unroll
        for (int g = 0; g < 4; ++g)
            bb[g] = *(const bfrag*)(
                wb2 + (size_t)(q2v * 64 + g * 16 + lr) * 288 + tv * 32 + lg * 8);
    };
    bfrag pf_d0[4], pf_e0[4];
    loadB2(pf_d0, w, 0);
    if (w < 2) loadB2(pf_e0, 8, 0);
    __syncthreads();

    // ---- GEMM2: xs1L @ Wbig2, pool over g, bias+relu -> XS2 ----
    {   // full-tile task: q2 = w, all 8 m-tiles
        const int q2 = w;
        facc acc[8][4];
        #pragma unroll
        for (int ms = 0; ms < 8; ++ms)
            #pragma unroll
            for (int g = 0; g < 4; ++g)
                acc[ms][g] = (facc){0.f, 0.f, 0.f, 0.f};

        auto mstep8 = [&](bfrag (&bb)[4], int tv) {
            bfrag av[8];
            #pragma unroll
            for (int ms = 0; ms < 8; ++ms) {
                int m = ms * 16 + lr;
                av[ms] = *(const bfrag*)&xs1L[m * XS1_STRIDE + tv * 32 + lg * 8];
            }
            __builtin_amdgcn_s_setprio(1);
            #pragma unroll
            for (int g = 0; g < 4; ++g)
                #pragma unroll
                for (int ms = 0; ms < 8; ++ms)
                    acc[ms][g] = mfma16(av[ms], bb[g], acc[ms][g]);
            __builtin_amdgcn_s_setprio(0);
        };

        bfrag d0[4], d1[4];
        #pragma unroll
        for (int g = 0; g < 4; ++g) d0[g] = pf_d0[g];
        #pragma unroll 1
        for (int tp = 0; tp < 4; ++tp) {
            loadB2(d1, q2, 2 * tp + 1);
            mstep8(d0, 2 * tp);
            loadB2(d0, q2, 2 * tp + 2);
            mstep8(d1, 2 * tp + 1);
        }
        mstep8(d0, 8);

        #pragma unroll
        for (int ms = 0; ms < 8; ++ms)
            #pragma unroll
            for (int i = 0; i < 4; ++i) {
                float v = fmaxf(fmaxf(acc[ms][0][i], acc[ms][1][i]),
                                fmaxf(acc[ms][2][i], acc[ms][3][i]));
                v = fmaxf(v + bcv2, 0.f);
                if (c2 < 10) {
                    int mi = ms * 16 + lg * 4 + i;
                    int k = q2 * 10 + c2;
                    XS2[mi * 128 + (((k >> 3) ^ (mi & 7)) << 3) + (k & 7)] = f2bf(v);
                }
            }
    }

    if (w < 2) {   // half-tile task: q2 = 8, m-half per wave
        const int q2 = 8;
        const int mBase = w * 64;
        facc acc[4][4];
        #pragma unroll
        for (int ms = 0; ms < 4; ++ms)
            #pragma unroll
            for (int g = 0; g < 4; ++g)
                acc[ms][g] = (facc){0.f, 0.f, 0.f, 0.f};

        auto mstep4 = [&](bfrag (&bb)[4], int tv) {
            bfrag av[4];
            #pragma unroll
            for (int ms = 0; ms < 4; ++ms) {
                int m = mBase + ms * 16 + lr;
                av[ms] = *(const bfrag*)&xs1L[m * XS1_STRIDE + tv * 32 + lg * 8];
            }
            __builtin_amdgcn_s_setprio(1);
            #pragma unroll
            for (int g = 0; g < 4; ++g)
                #pragma unroll
                for (int ms = 0; ms < 4; ++ms)
                    acc[ms][g] = mfma16(av[ms], bb[g], acc[ms][g]);
            __builtin_amdgcn_s_setprio(0);
        };

        bfrag d0[4], d1[4];
        #pragma unroll
        for (int g = 0; g < 4; ++g) d0[g] = pf_e0[g];
        #pragma unroll 1
        for (int tp = 0; tp < 4; ++tp) {
            loadB2(d1, q2, 2 * tp + 1);
            mstep4(d0, 2 * tp);
            loadB2(d0, q2, 2 * tp + 2);
            mstep4(d1, 2 * tp + 1);
        }
        mstep4(d0, 8);

        #pragma unroll
        for (int ms = 0; ms < 4; ++ms)
            #pragma unroll
            for (int i = 0; i < 4; ++i) {
                float v = fmaxf(fmaxf(acc[ms][0][i], acc[ms][1][i]),
                                fmaxf(acc[ms][2][i], acc[ms][3][i]));
                v = fmaxf(v + bcv2, 0.f);
                if (c2 < 10) {
                    int mi = mBase + ms * 16 + lg * 4 + i;
                    int k = 80 + c2;
                    XS2[mi * 128 + (((k >> 3) ^ (mi & 7)) << 3) + (k & 7)] = f2bf(v);
                }
            }
    }

    // ---- pre-barrier prefetch of FC1 weight fragments (global) ----
    bfrag w1f[3];
    {
        const int nt = w & 1;
        #pragma unroll
        for (int t = 0; t < 3; ++t)
            w1f[t] = *(const bfrag*)(w1t + (size_t)(nt * 16 + lr) * 96 + t * 32 + lg * 8);
    }
    __syncthreads();

    // ---- FC1: relu(xs2 @ W1 + b1) -> FC1 lds (4 mgrp x 2 ngrp, ms=2) ----
    {
        const int mg2 = w >> 1, nt = w & 1;
        facc acc[2];
        acc[0] = (facc){0.f, 0.f, 0.f, 0.f};
        acc[1] = (facc){0.f, 0.f, 0.f, 0.f};
        #pragma unroll
        for (int t = 0; t < 3; ++t) {
            #pragma unroll
            for (int ms = 0; ms < 2; ++ms) {
                int m = mg2 * 32 + ms * 16 + lr;
                bfrag av = *(const bfrag*)&XS2[m * 128 + (((t * 4 + lg) ^ (m & 7)) << 3)];
                acc[ms] = mfma16(av, w1f[t], acc[ms]);
            }
        }
        const int jcol = nt * 16 + lr;
        const float bj = b1[jcol];
        #pragma unroll
        for (int ms = 0; ms < 2; ++ms)
            #pragma unroll
            for (int i = 0; i < 4; ++i) {
                float v = fmaxf(acc[ms][i] + bj, 0.f);
                int mi = mg2 * 32 + ms * 16 + lg * 4 + i;
                FC1[mi * 64 + (((jcol >> 3) ^ (mi & 7)) << 3) + (jcol & 7)] = f2bf(v);
            }
    }

    // ---- pre-barrier prefetch of FC2 weight fragment ----
    bfrag w2f;
    if (w < 4) w2f = *(const bfrag*)(w2t + (size_t)lr * 32 + lg * 8);
    __syncthreads();

    // ---- FC2: theta = (fc1 @ W2 + b2) / (1+1e-5) -> global ws ----
    if (w < 4) {
        facc acc[2];
        acc[0] = (facc){0.f, 0.f, 0.f, 0.f};
        acc[1] = (facc){0.f, 0.f, 0.f, 0.f};
        #pragma unroll
        for (int ms = 0; ms < 2; ++ms) {
            int m = w * 32 + ms * 16 + lr;
            bfrag av = *(const bfrag*)&FC1[m * 64 + ((lg ^ (m & 7)) << 3)];
            acc[ms] = mfma16(av, w2f, acc[ms]);
        }
        if (lr < 6) {
            const float tb = b2[lr];
            const float inv = 1.0f / (1.0f + 1e-5f);
            #pragma unroll
            for (int ms = 0; ms < 2; ++ms)
                #pragma unroll
                for (int i = 0; i < 4; ++i) {
                    long long img = blkbase + w * 32 + ms * 16 + lg * 4 + i;
                    if (img < B) theta[img * 6 + lr] = (acc[ms][i] + tb) * inv;
                }
        }
    }
}

// ---------------------------------------------------------------------------
// K3: affine grid + bilinear sample; 64 images staged in LDS per block
// ---------------------------------------------------------------------------
__global__ __launch_bounds__(256) void k3_sample(
    const float* __restrict__ x, const float* __restrict__ theta,
    float* __restrict__ out, int B)
{
    __shared__ float xL[64 * 145];
    __shared__ float thL[64 * 6];
    const int tid = threadIdx.x;
    const long long blkbase = (long long)blockIdx.x * 64;

    const float4* xg4 = (const float4*)(x + blkbase * 144);
    for (int q = tid; q < 2304; q += 256) {
        int il = q / 36, c4 = q - il * 36;
        float4 v = make_float4(0.f, 0.f, 0.f, 0.f);
        if (blkbase + il < B) v = xg4[(size_t)il * 36 + c4];
        *(float4*)&xL[il * 145 + c4 * 4] = v;
    }
    for (int q = tid; q < 384; q += 256) {
        long long idx = blkbase * 6 + q;
        if (idx < (long long)B * 6) thL[q] = theta[idx];
    }
    __syncthreads();

    const int il = tid >> 2, quad = tid & 3;
    const long long img = blkbase + il;
    if (img >= B) return;

    const float t0 = thL[il * 6 + 0];
    const float t1 = thL[il * 6 + 1];
    const float t2 = thL[il * 6 + 2];
    const float t3 = thL[il * 6 + 3];
    const float t4 = thL[il * 6 + 4];
    const float t5 = thL[il * 6 + 5];
    const float* xr = &xL[il * 145];
    const float step = 2.0f / 11.0f;
    const float t0s = t0 * 5.5f, t3s = t3 * 5.5f;

    float o[36];
    #pragma unroll
    for (int rr = 0; rr < 3; ++rr) {
        const int iy = quad * 3 + rr;
        const float yn = -1.0f + iy * step;
        const float cx = (t1 * yn + t2 + 1.0f) * 5.5f;
        const float cy = (t4 * yn + t5 + 1.0f) * 5.5f;
        #pragma unroll
        for (int jx = 0; jx < 12; ++jx) {
            const float xn = -1.0f + jx * step;
            const float px = fmaf(t0s, xn, cx);
            const float py = fmaf(t3s, xn, cy);
            const float fy = floorf(py), fx = floorf(px);
            const float wy = py - fy,    wx = px - fx;
            const int ly = (int)fy, lx = (int)fx;
            const int y0 = refl12(ly), y1 = refl12(ly + 1);
            const int x0 = refl12(lx), x1 = refl12(lx + 1);
            const float v00 = xr[y0 * 12 + x0];
            const float v01 = xr[y0 * 12 + x1];
            const float v10 = xr[y1 * 12 + x0];
            const float v11 = xr[y1 * 12 + x1];
            const float r0 = v00 + wx * (v01 - v00);
            const float r1 = v10 + wx * (v11 - v10);
            o[rr * 12 + jx] = r0 + wy * (r1 - r0);
        }
    }
    float* op = out + (size_t)img * 144 + quad * 36;
    #pragma unroll
    for (int k = 0; k < 9; ++k)
        *(float4*)(op + 4 * k) = make_float4(o[4*k], o[4*k+1], o[4*k+2], o[4*k+3]);
}

extern "C" void kernel_launch(void* const* d_in, const int* in_sizes, int n_in,
                              void* d_out, int out_size, void* d_ws, size_t ws_size,
                              hipStream_t stream)
{
    const float* x   = (const float*)d_in[0];
    const float* k1w = (const float*)d_in[1];
    const float* bc1 = (const float*)d_in[2];
    const float* k2w = (const float*)d_in[3];
    const float* bc2 = (const float*)d_in[4];
    const float* W1  = (const float*)d_in[5];
    const float* b1  = (const float*)d_in[6];
    const float* W2  = (const float*)d_in[7];
    const float* b2  = (const float*)d_in[8];
    float* out = (float*)d_out;
    const int B = in_sizes[0] / 144;

    short* ws = (short*)d_ws;
    short* wb1 = ws + WB1_E;
    short* wb2 = ws + WB2_E;
    short* w1t = ws + W1T_E;
    short* w2t = ws + W2T_E;
    float* theta = (float*)((char*)d_ws + 707584);

    hipLaunchKernelGGL(k0_build, dim3(512), dim3(256), 0, stream,
                       k1w, bc1, k2w, W1, W2, ws);

    const int nb = (B + 127) / 128;
    hipLaunchKernelGGL(k12_gemm, dim3(nb), dim3(512), 0, stream,
                       x, wb1, wb2, w1t, w2t, bc2, b1, b2, theta, B);

    const int nb3 = (int)((B + 63) / 64);
    hipLaunchKernelGGL(k3_sample, dim3(nb3), dim3(256), 0, stream,
                       x, theta, out, B);
}

// Round 15
// 162.672 us; speedup vs baseline: 1.5093x; 1.0329x over previous
//
#include <hip/hip_runtime.h>
#include <hip/hip_bf16.h>

typedef __attribute__((ext_vector_type(8))) short bfrag;   // 8 x bf16
typedef __attribute__((ext_vector_type(4))) float facc;    // mfma accumulator

__device__ __forceinline__ short f2bf(float f) {
    __hip_bfloat16 h = __float2bfloat16(f);   // RTNE; compiler may emit HW cvt
    return __builtin_bit_cast(short, h);
}
__device__ __forceinline__ float maxpair8(float p) {
    // max(p[lane], p[lane^8]) within 16-lane rows; row_ror:8 == xor 8 (mod 16).
    int r = __builtin_amdgcn_update_dpp(0, __float_as_int(p),
                                        0x128 /*row_ror:8*/, 0xf, 0xf, true);
    return fmaxf(p, __int_as_float(r));
}
__device__ __forceinline__ int refl12(int i) {
    int r = i % 24; if (r < 0) r += 24; return (r < 12) ? r : 23 - r;
}
__device__ __forceinline__ facc mfma16(bfrag a, bfrag b, facc c) {
    return __builtin_amdgcn_mfma_f32_16x16x32_bf16(a, b, c, 0, 0, 0);
}

// ws layout (element offsets in shorts)
#define WB1_E 0                         // [1152][160] bf16  (col 144 = bias)
#define WB2_E 184320                    // [576][288]  bf16
#define W1T_E 350208                    // [32][96]    bf16
#define W2T_E 353280                    // [16][32]    bf16
// theta (float, [B][6]) at byte offset 707584

#define XS1_STRIDE 296                  // shorts; 592B: 16B-aligned, bank-clean

// ---------------------------------------------------------------------------
// K0: expand conv/FC weights into GEMM-friendly bf16 matrices in ws
// ---------------------------------------------------------------------------
__global__ void k0_build(const float* __restrict__ k1w, const float* __restrict__ bc1,
                         const float* __restrict__ k2w,
                         const float* __restrict__ W1, const float* __restrict__ W2,
                         short* __restrict__ ws)
{
    const int NW1 = 1152 * 160, NW2 = 576 * 288, NT1 = 32 * 96, NT2 = 16 * 32;
    const int total = NW1 + NW2 + NT1 + NT2;
    for (int q = blockIdx.x * blockDim.x + threadIdx.x; q < total;
         q += gridDim.x * blockDim.x) {
        float val = 0.f;
        short* dst;
        if (q < NW1) {
            int n = q / 160, kk = q - n * 160;
            dst = ws + WB1_E + q;
            int p1 = n >> 5, r = n & 31;
            int hy = (r >> 4) & 1, hx = (r >> 3) & 1, c = r & 7;
            int yp = p1 / 6, xp = p1 - yp * 6;
            int y = 2 * yp + hy, xo = 2 * xp + hx;
            if (kk < 144) {
                int yi = kk / 12, xi = kk - yi * 12;
                int ky = yi - y + 3, kx = xi - xo + 3;
                if (ky >= 0 && ky < 7 && kx >= 0 && kx < 7)
                    val = k1w[(ky * 7 + kx) * 8 + c];
            } else if (kk == 144) {
                val = bc1[c];                 // bias folded into K (A[144] = 1)
            }
        } else if (q < NW1 + NW2) {
            int qq = q - NW1;
            int n = qq / 288, k2 = qq - n * 288;
            dst = ws + WB2_E + qq;
            int q2 = n >> 6, r = n & 63, g = r >> 4, c2 = r & 15;
            int gy = g >> 1, gx = g & 1;
            int qy = q2 / 3, qx = q2 - qy * 3;
            int Y = 2 * qy + gy, X = 2 * qx + gx;
            int p1 = k2 >> 3, c1 = k2 & 7;
            int yp = p1 / 6, xp = p1 - yp * 6;
            int ky = yp - Y + 2, kx = xp - X + 2;
            if (c2 < 10 && ky >= 0 && ky < 5 && kx >= 0 && kx < 5)
                val = k2w[((ky * 5 + kx) * 8 + c1) * 10 + c2];
        } else if (q < NW1 + NW2 + NT1) {
            int qq = q - NW1 - NW2;
            int j = qq / 96, k = qq - j * 96;
            dst = ws + W1T_E + qq;
            if (k < 90) val = W1[k * 32 + j];
        } else {
            int qq = q - NW1 - NW2 - NT1;
            int t = qq / 32, k = qq - t * 32;
            dst = ws + W2T_E + qq;
            if (t < 6) val = W2[k * 6 + t];
        }
        *dst = f2bf(val);
    }
}

// ---------------------------------------------------------------------------
// K12: GEMM1 (x @ Wbig1, pool+relu -> xs1 in LDS) + GEMM2 (+pool+relu)
//      + FC1 + FC2 -> theta[B][6] in ws.  xs1 never touches HBM.
//      512 thr = 8 waves, 128 images/block.
//      GEMM1: double-acc pipeline, bias-in-K, setprio on MFMA bursts.
//      GEMM2: wave w owns q2=w (ms=8); q2=8 split over waves 0/1.
// ---------------------------------------------------------------------------
__global__ __launch_bounds__(512) void k12_gemm(
    const float* __restrict__ x, const short* __restrict__ wb1,
    const short* __restrict__ wb2, const short* __restrict__ w1t,
    const short* __restrict__ w2t, const float* __restrict__ bc2,
    const float* __restrict__ b1, const float* __restrict__ b2,
    float* __restrict__ theta, int B)
{
    __shared__ short xs1L[128 * XS1_STRIDE];  // 75.8 KB
    __shared__ short XS2[128 * 128];          // 32 KB, XOR-swizzled
    __shared__ short FC1[128 * 64];           // 16 KB, XOR-swizzled

    const int tid = threadIdx.x;
    const int l = tid & 63, w = tid >> 6;     // 8 waves
    const int mg = w >> 2, ng = w & 3;        // GEMM1: 2 Mgrp x 4 Ngrp
    const int lr = l & 15, lg = l >> 4;
    const long long blkbase = (long long)blockIdx.x * 128;
    const int mloc = mg * 64;                 // GEMM1 wave image base

    // zero XS2 pad (cols 90..127 must be 0 for FC1)
    for (int q = tid; q < 2048; q += 512) {
        bfrag z = {0, 0, 0, 0, 0, 0, 0, 0};
        *(bfrag*)&XS2[q * 8] = z;
    }

    // ---- GEMM1: A fragments from global x (f32 -> bf16, registers) ----
    bfrag a[4][5];
    #pragma unroll
    for (int ms = 0; ms < 4; ++ms) {
        long long img = blkbase + mloc + ms * 16 + lr;
        if (img >= B) img = B - 1;
        const float* row = x + (size_t)img * 144;
        #pragma unroll
        for (int t = 0; t < 5; ++t) {
            const int k = t * 32 + lg * 8;
            bfrag f = {0, 0, 0, 0, 0, 0, 0, 0};
            if (k < 144) {
                float4 u0 = *(const float4*)(row + k);
                float4 u1 = *(const float4*)(row + k + 4);
                f[0] = f2bf(u0.x); f[1] = f2bf(u0.y);
                f[2] = f2bf(u0.z); f[3] = f2bf(u0.w);
                f[4] = f2bf(u1.x); f[5] = f2bf(u1.y);
                f[6] = f2bf(u1.z); f[7] = f2bf(u1.w);
            } else if (k == 144) {
                f[0] = (short)0x3F80;         // 1.0 bf16 -> bias term
            }
            a[ms][t] = f;
        }
    }

    auto loadB1 = [&](bfrag (&bb)[2][5], int p1v) {
        const short* p = wb1 + (size_t)(p1v * 32 + lr) * 160 + lg * 8;
        #pragma unroll
        for (int nt = 0; nt < 2; ++nt)
            #pragma unroll
            for (int t = 0; t < 5; ++t)
                bb[nt][t] = *(const bfrag*)(p + (size_t)nt * 16 * 160 + t * 32);
    };
    auto mfma1 = [&](bfrag (&bb)[2][5], facc (&acc)[4][2]) {
        #pragma unroll
        for (int ms = 0; ms < 4; ++ms)
            #pragma unroll
            for (int nt = 0; nt < 2; ++nt)
                acc[ms][nt] = (facc){0.f, 0.f, 0.f, 0.f};
        __builtin_amdgcn_s_setprio(1);
        #pragma unroll
        for (int t = 0; t < 5; ++t)
            #pragma unroll
            for (int nt = 0; nt < 2; ++nt)
                #pragma unroll
                for (int ms = 0; ms < 4; ++ms)
                    acc[ms][nt] = mfma16(a[ms][t], bb[nt][t], acc[ms][nt]);
        __builtin_amdgcn_s_setprio(0);
    };
    auto epi1 = [&](facc (&acc)[4][2], int p1v) {
        // pool (nt pools hy; DPP ror8 pools hx) + relu + store (bias in K)
        #pragma unroll
        for (int ms = 0; ms < 4; ++ms)
            #pragma unroll
            for (int i = 0; i < 4; ++i) {
                float p = fmaxf(acc[ms][0][i], acc[ms][1][i]);
                p = maxpair8(p);
                p = fmaxf(p, 0.f);
                if ((l & 15) < 8) {
                    int mi = mloc + ms * 16 + lg * 4 + i;
                    xs1L[mi * XS1_STRIDE + p1v * 8 + (l & 7)] = f2bf(p);
                }
            }
    };

    {   // chunk c -> p1 = 4c + ng, c = 0..8.  Pipeline: epi(j) under mfma(j+1).
        bfrag c0[2][5], c1[2][5];
        facc accA[4][2], accB[4][2];
        loadB1(c0, ng);
        mfma1(c0, accA);                         // chunk 0
        loadB1(c1, 4 + ng);                      // B chunk 1
        #pragma unroll 1
        for (int jp = 0; jp < 4; ++jp) {
            mfma1(c1, accB);                     // chunk 2jp+1
            loadB1(c0, (2 * jp + 2) * 4 + ng);   // B chunk 2jp+2
            epi1(accA, (2 * jp) * 4 + ng);       // epi chunk 2jp  (|| mfma above)
            mfma1(c0, accA);                     // chunk 2jp+2
            if (jp < 3) loadB1(c1, (2 * jp + 3) * 4 + ng);
            epi1(accB, (2 * jp + 1) * 4 + ng);   // epi chunk 2jp+1
        }
        epi1(accA, 32 + ng);                     // chunk 8
    }

    // ---- pre-barrier prefetch of GEMM2's first B fragments (global) ----
    const int c2 = lr;
    const float bcv2 = (c2 < 10) ? bc2[c2] : 0.f;

    auto loadB2 = [&](bfrag (&bb)[4], int q2v, int tv) {
        #pragma unroll
        for (int g = 0; g < 4; ++g)
            bb[g] = *(const bfrag*)(
                wb2 + (size_t)(q2v * 64 + g * 16 + lr) * 288 + tv * 32 + lg * 8);
    };
    bfrag pf_d0[4], pf_e0[4];
    loadB2(pf_d0, w, 0);
    if (w < 2) loadB2(pf_e0, 8, 0);
    __syncthreads();

    // ---- GEMM2: xs1L @ Wbig2, pool over g, bias+relu -> XS2 ----
    {   // full-tile task: q2 = w, all 8 m-tiles
        const int q2 = w;
        facc acc[8][4];
        #pragma unroll
        for (int ms = 0; ms < 8; ++ms)
            #pragma unroll
            for (int g = 0; g < 4; ++g)
                acc[ms][g] = (facc){0.f, 0.f, 0.f, 0.f};

        auto mstep8 = [&](bfrag (&bb)[4], int tv) {
            bfrag av[8];
            #pragma unroll
            for (int ms = 0; ms < 8; ++ms) {
                int m = ms * 16 + lr;
                av[ms] = *(const bfrag*)&xs1L[m * XS1_STRIDE + tv * 32 + lg * 8];
            }
            __builtin_amdgcn_s_setprio(1);
            #pragma unroll
            for (int g = 0; g < 4; ++g)
                #pragma unroll
                for (int ms = 0; ms < 8; ++ms)
                    acc[ms][g] = mfma16(av[ms], bb[g], acc[ms][g]);
            __builtin_amdgcn_s_setprio(0);
        };

        bfrag d0[4], d1[4];
        #pragma unroll
        for (int g = 0; g < 4; ++g) d0[g] = pf_d0[g];
        #pragma unroll 1
        for (int tp = 0; tp < 4; ++tp) {
            loadB2(d1, q2, 2 * tp + 1);
            mstep8(d0, 2 * tp);
            loadB2(d0, q2, 2 * tp + 2);
            mstep8(d1, 2 * tp + 1);
        }
        mstep8(d0, 8);

        #pragma unroll
        for (int ms = 0; ms < 8; ++ms)
            #pragma unroll
            for (int i = 0; i < 4; ++i) {
                float v = fmaxf(fmaxf(acc[ms][0][i], acc[ms][1][i]),
                                fmaxf(acc[ms][2][i], acc[ms][3][i]));
                v = fmaxf(v + bcv2, 0.f);
                if (c2 < 10) {
                    int mi = ms * 16 + lg * 4 + i;
                    int k = q2 * 10 + c2;
                    XS2[mi * 128 + (((k >> 3) ^ (mi & 7)) << 3) + (k & 7)] = f2bf(v);
                }
            }
    }

    if (w < 2) {   // half-tile task: q2 = 8, m-half per wave
        const int q2 = 8;
        const int mBase = w * 64;
        facc acc[4][4];
        #pragma unroll
        for (int ms = 0; ms < 4; ++ms)
            #pragma unroll
            for (int g = 0; g < 4; ++g)
                acc[ms][g] = (facc){0.f, 0.f, 0.f, 0.f};

        auto mstep4 = [&](bfrag (&bb)[4], int tv) {
            bfrag av[4];
            #pragma unroll
            for (int ms = 0; ms < 4; ++ms) {
                int m = mBase + ms * 16 + lr;
                av[ms] = *(const bfrag*)&xs1L[m * XS1_STRIDE + tv * 32 + lg * 8];
            }
            __builtin_amdgcn_s_setprio(1);
            #pragma unroll
            for (int g = 0; g < 4; ++g)
                #pragma unroll
                for (int ms = 0; ms < 4; ++ms)
                    acc[ms][g] = mfma16(av[ms], bb[g], acc[ms][g]);
            __builtin_amdgcn_s_setprio(0);
        };

        bfrag d0[4], d1[4];
        #pragma unroll
        for (int g = 0; g < 4; ++g) d0[g] = pf_e0[g];
        #pragma unroll 1
        for (int tp = 0; tp < 4; ++tp) {
            loadB2(d1, q2, 2 * tp + 1);
            mstep4(d0, 2 * tp);
            loadB2(d0, q2, 2 * tp + 2);
            mstep4(d1, 2 * tp + 1);
        }
        mstep4(d0, 8);

        #pragma unroll
        for (int ms = 0; ms < 4; ++ms)
            #pragma unroll
            for (int i = 0; i < 4; ++i) {
                float v = fmaxf(fmaxf(acc[ms][0][i], acc[ms][1][i]),
                                fmaxf(acc[ms][2][i], acc[ms][3][i]));
                v = fmaxf(v + bcv2, 0.f);
                if (c2 < 10) {
                    int mi = mBase + ms * 16 + lg * 4 + i;
                    int k = 80 + c2;
                    XS2[mi * 128 + (((k >> 3) ^ (mi & 7)) << 3) + (k & 7)] = f2bf(v);
                }
            }
    }

    // ---- pre-barrier prefetch of FC1 weight fragments (global) ----
    bfrag w1f[3];
    {
        const int nt = w & 1;
        #pragma unroll
        for (int t = 0; t < 3; ++t)
            w1f[t] = *(const bfrag*)(w1t + (size_t)(nt * 16 + lr) * 96 + t * 32 + lg * 8);
    }
    __syncthreads();

    // ---- FC1: relu(xs2 @ W1 + b1) -> FC1 lds (4 mgrp x 2 ngrp, ms=2) ----
    {
        const int mg2 = w >> 1, nt = w & 1;
        facc acc[2];
        acc[0] = (facc){0.f, 0.f, 0.f, 0.f};
        acc[1] = (facc){0.f, 0.f, 0.f, 0.f};
        #pragma unroll
        for (int t = 0; t < 3; ++t) {
            #pragma unroll
            for (int ms = 0; ms < 2; ++ms) {
                int m = mg2 * 32 + ms * 16 + lr;
                bfrag av = *(const bfrag*)&XS2[m * 128 + (((t * 4 + lg) ^ (m & 7)) << 3)];
                acc[ms] = mfma16(av, w1f[t], acc[ms]);
            }
        }
        const int jcol = nt * 16 + lr;
        const float bj = b1[jcol];
        #pragma unroll
        for (int ms = 0; ms < 2; ++ms)
            #pragma unroll
            for (int i = 0; i < 4; ++i) {
                float v = fmaxf(acc[ms][i] + bj, 0.f);
                int mi = mg2 * 32 + ms * 16 + lg * 4 + i;
                FC1[mi * 64 + (((jcol >> 3) ^ (mi & 7)) << 3) + (jcol & 7)] = f2bf(v);
            }
    }

    // ---- pre-barrier prefetch of FC2 weight fragment ----
    bfrag w2f;
    if (w < 4) w2f = *(const bfrag*)(w2t + (size_t)lr * 32 + lg * 8);
    __syncthreads();

    // ---- FC2: theta = (fc1 @ W2 + b2) / (1+1e-5) -> global ws ----
    if (w < 4) {
        facc acc[2];
        acc[0] = (facc){0.f, 0.f, 0.f, 0.f};
        acc[1] = (facc){0.f, 0.f, 0.f, 0.f};
        #pragma unroll
        for (int ms = 0; ms < 2; ++ms) {
            int m = w * 32 + ms * 16 + lr;
            bfrag av = *(const bfrag*)&FC1[m * 64 + ((lg ^ (m & 7)) << 3)];
            acc[ms] = mfma16(av, w2f, acc[ms]);
        }
        if (lr < 6) {
            const float tb = b2[lr];
            const float inv = 1.0f / (1.0f + 1e-5f);
            #pragma unroll
            for (int ms = 0; ms < 2; ++ms)
                #pragma unroll
                for (int i = 0; i < 4; ++i) {
                    long long img = blkbase + w * 32 + ms * 16 + lg * 4 + i;
                    if (img < B) theta[img * 6 + lr] = (acc[ms][i] + tb) * inv;
                }
        }
    }
}

// ---------------------------------------------------------------------------
// K3: affine grid + bilinear sample; 64 images staged in LDS per block
// ---------------------------------------------------------------------------
__global__ __launch_bounds__(256) void k3_sample(
    const float* __restrict__ x, const float* __restrict__ theta,
    float* __restrict__ out, int B)
{
    __shared__ float xL[64 * 145];
    __shared__ float thL[64 * 6];
    const int tid = threadIdx.x;
    const long long blkbase = (long long)blockIdx.x * 64;

    const float4* xg4 = (const float4*)(x + blkbase * 144);
    for (int q = tid; q < 2304; q += 256) {
        int il = q / 36, c4 = q - il * 36;
        float4 v = make_float4(0.f, 0.f, 0.f, 0.f);
        if (blkbase + il < B) v = xg4[(size_t)il * 36 + c4];
        *(float4*)&xL[il * 145 + c4 * 4] = v;
    }
    for (int q = tid; q < 384; q += 256) {
        long long idx = blkbase * 6 + q;
        if (idx < (long long)B * 6) thL[q] = theta[idx];
    }
    __syncthreads();

    const int il = tid >> 2, quad = tid & 3;
    const long long img = blkbase + il;
    if (img >= B) return;

    const float t0 = thL[il * 6 + 0];
    const float t1 = thL[il * 6 + 1];
    const float t2 = thL[il * 6 + 2];
    const float t3 = thL[il * 6 + 3];
    const float t4 = thL[il * 6 + 4];
    const float t5 = thL[il * 6 + 5];
    const float* xr = &xL[il * 145];
    const float step = 2.0f / 11.0f;
    const float t0s = t0 * 5.5f, t3s = t3 * 5.5f;

    float o[36];
    #pragma unroll
    for (int rr = 0; rr < 3; ++rr) {
        const int iy = quad * 3 + rr;
        const float yn = -1.0f + iy * step;
        const float cx = (t1 * yn + t2 + 1.0f) * 5.5f;
        const float cy = (t4 * yn + t5 + 1.0f) * 5.5f;
        #pragma unroll
        for (int jx = 0; jx < 12; ++jx) {
            const float xn = -1.0f + jx * step;
            const float px = fmaf(t0s, xn, cx);
            const float py = fmaf(t3s, xn, cy);
            const float fy = floorf(py), fx = floorf(px);
            const float wy = py - fy,    wx = px - fx;
            const int ly = (int)fy, lx = (int)fx;
            const int y0 = refl12(ly), y1 = refl12(ly + 1);
            const int x0 = refl12(lx), x1 = refl12(lx + 1);
            const float v00 = xr[y0 * 12 + x0];
            const float v01 = xr[y0 * 12 + x1];
            const float v10 = xr[y1 * 12 + x0];
            const float v11 = xr[y1 * 12 + x1];
            const float r0 = v00 + wx * (v01 - v00);
            const float r1 = v10 + wx * (v11 - v10);
            o[rr * 12 + jx] = r0 + wy * (r1 - r0);
        }
    }
    float* op = out + (size_t)img * 144 + quad * 36;
    #pragma unroll
    for (int k = 0; k < 9; ++k)
        *(float4*)(op + 4 * k) = make_float4(o[4*k], o[4*k+1], o[4*k+2], o[4*k+3]);
}

extern "C" void kernel_launch(void* const* d_in, const int* in_sizes, int n_in,
                              void* d_out, int out_size, void* d_ws, size_t ws_size,
                              hipStream_t stream)
{
    const float* x   = (const float*)d_in[0];
    const float* k1w = (const float*)d_in[1];
    const float* bc1 = (const float*)d_in[2];
    const float* k2w = (const float*)d_in[3];
    const float* bc2 = (const float*)d_in[4];
    const float* W1  = (const float*)d_in[5];
    const float* b1  = (const float*)d_in[6];
    const float* W2  = (const float*)d_in[7];
    const float* b2  = (const float*)d_in[8];
    float* out = (float*)d_out;
    const int B = in_sizes[0] / 144;

    short* ws = (short*)d_ws;
    short* wb1 = ws + WB1_E;
    short* wb2 = ws + WB2_E;
    short* w1t = ws + W1T_E;
    short* w2t = ws + W2T_E;
    float* theta = (float*)((char*)d_ws + 707584);

    hipLaunchKernelGGL(k0_build, dim3(512), dim3(256), 0, stream,
                       k1w, bc1, k2w, W1, W2, ws);

    const int nb = (B + 127) / 128;
    hipLaunchKernelGGL(k12_gemm, dim3(nb), dim3(512), 0, stream,
                       x, wb1, wb2, w1t, w2t, bc2, b1, b2, theta, B);

    const int nb3 = (int)((B + 63) / 64);
    hipLaunchKernelGGL(k3_sample, dim3(nb3), dim3(256), 0, stream,
                       x, theta, out, B);
}